// Round 12
// baseline (303.648 us; speedup 1.0000x reference)
//
#include <hip/hip_runtime.h>

#define LQ 2048
#define LK 2048
#define BB 16
#define DD 512
#define DKK 64
#define EPSF 1e-9f

typedef unsigned short u16;
typedef unsigned char u8;
typedef long i64;
typedef __attribute__((ext_vector_type(8))) short bf16x8;
typedef __attribute__((ext_vector_type(4))) float f32x4;
#define MFMA16(a, b, c) __builtin_amdgcn_mfma_f32_16x16x32_bf16(a, b, c, 0, 0, 0)
#define MFMAF8(a, b, c) __builtin_amdgcn_mfma_f32_16x16x32_fp8_fp8(a, b, c, 0, 0, 0)

__device__ inline u16 f2bf(float f) {
    unsigned int u = __float_as_uint(f);
    u += 0x7fffu + ((u >> 16) & 1u);   // RNE
    return (u16)(u >> 16);
}
__device__ inline bf16x8 cvt8(float4 a, float4 b) {
    bf16x8 r;
    r[0] = (short)f2bf(a.x); r[1] = (short)f2bf(a.y); r[2] = (short)f2bf(a.z); r[3] = (short)f2bf(a.w);
    r[4] = (short)f2bf(b.x); r[5] = (short)f2bf(b.y); r[6] = (short)f2bf(b.z); r[7] = (short)f2bf(b.w);
    return r;
}
__device__ inline int pk_fp8x4(float a, float b, float c, float d) {
    int r = __builtin_amdgcn_cvt_pk_fp8_f32(a, b, 0, false);
    r = __builtin_amdgcn_cvt_pk_fp8_f32(c, d, r, true);
    return r;
}
__device__ inline void gload16(const void* g, void* l) {
    __builtin_amdgcn_global_load_lds((const __attribute__((address_space(1))) unsigned int*)g,
                                     (__attribute__((address_space(3))) unsigned int*)l, 16, 0, 0);
}

__global__ __launch_bounds__(256) void k_cvt(const float* __restrict__ src, u16* __restrict__ dst, int n) {
    int i = (blockIdx.x * 256 + threadIdx.x) * 4;
    if (i < n) {
        float4 v = *reinterpret_cast<const float4*>(src + i);
        *reinterpret_cast<ushort4*>(dst + i) = make_ushort4(f2bf(v.x), f2bf(v.y), f2bf(v.z), f2bf(v.w));
    }
}

// value f32 [LK][B][D] -> vb bf16 [B][LK][D]
__global__ __launch_bounds__(256) void k_cvtv(const float* __restrict__ value, u16* __restrict__ vb) {
    size_t i = ((size_t)blockIdx.x * 256 + threadIdx.x) * 8;
    int k = (int)(i >> 13);
    int r = (int)(i & 8191);
    int b = r >> 9, d = r & 511;
    float4 a = *reinterpret_cast<const float4*>(value + i);
    float4 c = *reinterpret_cast<const float4*>(value + i + 4);
    *reinterpret_cast<bf16x8*>(vb + ((size_t)b * LK + k) * DD + d) = cvt8(a, c);
}

// fused q/k projection + l2norm
__global__ __launch_bounds__(256) void k_projqk(const float* __restrict__ xq, const float* __restrict__ xk,
                                                const u16* __restrict__ Wq, const u16* __restrict__ Wk,
                                                u16* __restrict__ yq, u16* __restrict__ yk)
{
    const float* x = blockIdx.z ? xk : xq;
    const u16* Wb = blockIdx.z ? Wk : Wq;
    u16* y = blockIdx.z ? yk : yq;
    const int b = blockIdx.y, r0 = blockIdx.x * 64;
    const int tid = threadIdx.x, wave = tid >> 6, lane = tid & 63, l15 = lane & 15, g = lane >> 4;
    const int rw = r0 + wave * 16;
    f32x4 z = {0.f, 0.f, 0.f, 0.f};
    f32x4 acc[4];
#pragma unroll
    for (int nf = 0; nf < 4; nf++) acc[nf] = z;

    for (int kt = 0; kt < DD; kt += 32) {
        const float* p = x + ((size_t)(rw + l15) * BB + b) * DD + kt + g * 8;
        bf16x8 af = cvt8(*reinterpret_cast<const float4*>(p), *reinterpret_cast<const float4*>(p + 4));
#pragma unroll
        for (int nf = 0; nf < 4; nf++) {
            bf16x8 bf_ = *reinterpret_cast<const bf16x8*>(Wb + (size_t)(nf * 16 + l15) * DD + kt + g * 8);
            acc[nf] = MFMA16(af, bf_, acc[nf]);
        }
    }
    float rn[4];
#pragma unroll
    for (int j = 0; j < 4; j++) {
        float t2 = acc[0][j] * acc[0][j] + acc[1][j] * acc[1][j]
                 + acc[2][j] * acc[2][j] + acc[3][j] * acc[3][j];
        t2 += __shfl_xor(t2, 1, 64);
        t2 += __shfl_xor(t2, 2, 64);
        t2 += __shfl_xor(t2, 4, 64);
        t2 += __shfl_xor(t2, 8, 64);
        rn[j] = 1.f / fmaxf(sqrtf(t2), 1e-12f);
    }
#pragma unroll
    for (int nf = 0; nf < 4; nf++)
#pragma unroll
        for (int j = 0; j < 4; j++) {
            int q = rw + g * 4 + j;
            y[((size_t)b * LQ + q) * DKK + nf * 16 + l15] = f2bf(acc[nf][j] * rn[j]);
        }
}

// Single QK^T pass, TILED E0 output, software-pipelined (cur/next register dbuf).
// E0t layout: [qt][kt][16q][16k] bytes, tile = 256B.
// Rpart[bl][kt][q] = partial row sums.  grid (LK/64, LQ/512, G)
__global__ __launch_bounds__(256) void k_score(const u16* __restrict__ wqb, const u16* __restrict__ wkb,
                                               u8* __restrict__ E0t, float* __restrict__ Rpart, int b0)
{
    const int kb = blockIdx.x, qc = blockIdx.y, bl = blockIdx.z, b = b0 + bl;
    const int tid = threadIdx.x, w = tid >> 6, lane = tid & 63, l15 = lane & 15, g = lane >> 4;
    const int k0 = kb * 64, kt = kb * 4 + w;
    f32x4 z = {0.f, 0.f, 0.f, 0.f};

    const u16* ar = wkb + ((size_t)b * LK + k0 + w * 16 + l15) * DKK;
    bf16x8 af0 = *reinterpret_cast<const bf16x8*>(ar + g * 8);
    bf16x8 af1 = *reinterpret_cast<const bf16x8*>(ar + 32 + g * 8);
    u8* Eb = E0t + (size_t)bl * LQ * LK + ((size_t)(qc * 32) * 128 + kt) * 256 + l15 * 16 + g * 4;
    float* Rp = Rpart + ((size_t)bl * 128 + kt) * LQ + qc * 512;
    const u16* qbase = wqb + ((size_t)b * LQ + qc * 512 + l15) * DKK + g * 8;

    bf16x8 cb0[4], cb1[4], nb0[4], nb1[4];
#pragma unroll
    for (int j = 0; j < 4; j++) {
        const u16* br = qbase + (size_t)j * 16 * DKK;
        cb0[j] = *reinterpret_cast<const bf16x8*>(br);
        cb1[j] = *reinterpret_cast<const bf16x8*>(br + 32);
    }
#pragma unroll
    for (int mI = 0; mI < 8; mI++) {
        if (mI < 7) {
#pragma unroll
            for (int j = 0; j < 4; j++) {
                const u16* br = qbase + (size_t)((mI + 1) * 4 + j) * 16 * DKK;
                nb0[j] = *reinterpret_cast<const bf16x8*>(br);
                nb1[j] = *reinterpret_cast<const bf16x8*>(br + 32);
            }
        }
#pragma unroll
        for (int j = 0; j < 4; j++) {
            int qf = mI * 4 + j;
            f32x4 s = z;
            s = MFMA16(af0, cb0[j], s);
            s = MFMA16(af1, cb1[j], s);
            float pe0 = __expf(s[0]), pe1 = __expf(s[1]);
            float pe2 = __expf(s[2]), pe3 = __expf(s[3]);
            *reinterpret_cast<int*>(Eb + (size_t)qf * 32768) = pk_fp8x4(pe0, pe1, pe2, pe3);
            float v = pe0 + pe1 + pe2 + pe3;
            v += __shfl_xor(v, 16, 64);
            v += __shfl_xor(v, 32, 64);
            if (g == 0) Rp[qf * 16 + l15] = v;
        }
#pragma unroll
        for (int j = 0; j < 4; j++) { cb0[j] = nb0[j]; cb1[j] = nb1[j]; }
    }
}

// Rq[b][q] = 1 / sum_p Rpart[bl][p][q]
__global__ __launch_bounds__(256) void k_rsum(const float* __restrict__ Rpart, float* __restrict__ Rq, int b0) {
    int idx = blockIdx.x * 256 + threadIdx.x;
    int bl = idx >> 11, q = idx & 2047;
    const float* rp = Rpart + (size_t)bl * 128 * LQ + q;
    float s = 0.f;
    for (int p = 0; p < 128; p++) s += rp[(size_t)p * LQ];
    Rq[(size_t)(b0 + bl) * LQ + q] = 1.f / s;
}

// Cpart[bl][qc][k] = sum over 512 q (32 qt) of E0t[qt][kt]*Rq.  grid (32, 4, G)
__global__ __launch_bounds__(256) void k_colsum(const u8* __restrict__ E0t, const float* __restrict__ Rq,
                                                float* __restrict__ Cpart, int b0)
{
    const int qc = blockIdx.y, bl = blockIdx.z;
    const int tid = threadIdx.x, w = tid >> 6, lane = tid & 63, l15 = lane & 15, g = lane >> 4;
    const int kt = blockIdx.x * 4 + w;
    const u8* base = E0t + (size_t)bl * LQ * LK + (size_t)kt * 256 + l15 * 16 + g * 4;
    const float* rq = Rq + (size_t)(b0 + bl) * LQ;
    float acc[4] = {0.f, 0.f, 0.f, 0.f};
#pragma unroll 4
    for (int i = 0; i < 32; i++) {
        int qt = qc * 32 + i;
        unsigned int u = *reinterpret_cast<const unsigned int*>(base + (size_t)qt * 32768);
        float wgt = rq[qt * 16 + l15];
#pragma unroll
        for (int by = 0; by < 4; by++) {
            // e4m3fn -> f32 for positive normals (E0 in [0.37, 2.72])
            unsigned int f = 0x3C000000u + (((u >> (8 * by)) & 0x7Fu) << 20);
            acc[by] += __uint_as_float(f) * wgt;
        }
    }
#pragma unroll
    for (int by = 0; by < 4; by++) {
        acc[by] += __shfl_xor(acc[by], 1, 64);
        acc[by] += __shfl_xor(acc[by], 2, 64);
        acc[by] += __shfl_xor(acc[by], 4, 64);
        acc[by] += __shfl_xor(acc[by], 8, 64);
    }
    if (l15 == 0) {
        float4 v4 = make_float4(acc[0], acc[1], acc[2], acc[3]);
        *reinterpret_cast<float4*>(Cpart + ((size_t)bl * 4 + qc) * LK + kt * 16 + g * 4) = v4;
    }
}

// ci[b][k] = 1/(eps + sum_qc Cpart)
__global__ __launch_bounds__(256) void k_csum(const float* __restrict__ Cpart, float* __restrict__ ci, int b0) {
    int idx = blockIdx.x * 256 + threadIdx.x;
    int bl = idx >> 11, k = idx & 2047;
    const float* cp = Cpart + (size_t)bl * 4 * LK + k;
    float s = 0.f;
#pragma unroll
    for (int p = 0; p < 4; p++) s += cp[(size_t)p * LK];
    ci[(size_t)(b0 + bl) * LK + k] = 1.f / (EPSF + s);
}

// wvS[b][d][k] = fp8( (vb[b][k,:] @ WVb[d,:]) * ci[b][k] )  -- staged GEMM
__global__ __launch_bounds__(256, 3) void k_projv(const u16* __restrict__ vb, const u16* __restrict__ WVb,
                                                  const float* __restrict__ ci, u8* __restrict__ wvS, int b0)
{
    const int b = b0 + blockIdx.z, k0 = blockIdx.x * 128, n0 = blockIdx.y * 128;
    const int tid = threadIdx.x, wv = tid >> 6, lane = tid & 63, l15 = lane & 15, g = lane >> 4;
    const int qg = wv >> 1, dg = wv & 1;

    __shared__ __align__(16) u16 As[128 * 64], Bs[128 * 64];

    const int srow = wv * 8 + (lane >> 3);
    const int scb = ((lane & 7) * 16) ^ ((srow & 7) << 4);
    const char* gA = (const char*)(vb + ((size_t)b * LK + k0 + srow) * DD) + scb;
    const char* gB = (const char*)(WVb + (size_t)(n0 + srow) * DD) + scb;
    const size_t rstep = (size_t)32 * DD * 2;

    f32x4 z = {0.f, 0.f, 0.f, 0.f};
    f32x4 acc[4][4];
#pragma unroll
    for (int m = 0; m < 4; m++)
#pragma unroll
        for (int nf = 0; nf < 4; nf++) acc[m][nf] = z;

#pragma unroll
    for (int p = 0; p < 4; ++p) {
        gload16(gA + p * rstep, (char*)As + p * 4096 + wv * 1024);
        gload16(gB + p * rstep, (char*)Bs + p * 4096 + wv * 1024);
    }

    for (int tt = 0; tt < DD / 64; ++tt) {
        __syncthreads();
        bf16x8 af[4][2], bv[4][2];
#pragma unroll
        for (int m = 0; m < 4; m++) {
            int row = qg * 64 + m * 16 + l15;
            const char* rp = (const char*)As + row * 128;
            int x = (row & 7) << 4;
#pragma unroll
            for (int kk = 0; kk < 2; kk++)
                af[m][kk] = *reinterpret_cast<const bf16x8*>(rp + ((kk * 64 + g * 16) ^ x));
        }
#pragma unroll
        for (int nf = 0; nf < 4; nf++) {
            int row = dg * 64 + nf * 16 + l15;
            const char* rp = (const char*)Bs + row * 128;
            int x = (row & 7) << 4;
#pragma unroll
            for (int kk = 0; kk < 2; kk++)
                bv[nf][kk] = *reinterpret_cast<const bf16x8*>(rp + ((kk * 64 + g * 16) ^ x));
        }
        __syncthreads();
        if (tt + 1 < DD / 64) {
            int ktb = (tt + 1) * 128;
#pragma unroll
            for (int p = 0; p < 4; ++p) {
                gload16(gA + p * rstep + ktb, (char*)As + p * 4096 + wv * 1024);
                gload16(gB + p * rstep + ktb, (char*)Bs + p * 4096 + wv * 1024);
            }
        }
#pragma unroll
        for (int nf = 0; nf < 4; nf++)
#pragma unroll
            for (int m = 0; m < 4; m++) {
                acc[m][nf] = MFMA16(af[m][0], bv[nf][0], acc[m][nf]);
                acc[m][nf] = MFMA16(af[m][1], bv[nf][1], acc[m][nf]);
            }
    }
#pragma unroll
    for (int m = 0; m < 4; m++) {
        float cv[4];
        int kb = k0 + qg * 64 + m * 16 + g * 4;
#pragma unroll
        for (int j = 0; j < 4; j++) cv[j] = ci[(size_t)b * LK + kb + j];
#pragma unroll
        for (int nf = 0; nf < 4; nf++) {
            int d = n0 + dg * 64 + nf * 16 + l15;
            *reinterpret_cast<int*>(wvS + ((size_t)b * DD + d) * LK + kb) =
                pk_fp8x4(acc[m][nf][0] * cv[0], acc[m][nf][1] * cv[1],
                         acc[m][nf][2] * cv[2], acc[m][nf][3] * cv[3]);
        }
    }
}

// t[q,b,:] = query - Rq[q] * (E0t @ wvS^T).  fp8 GEMM, BK=128.
// A (E0t) is tiled [qt][kt][16][16]: staged as 8 contiguous 2KB runs, LDS linear.
__global__ __launch_bounds__(256, 3) void k_pvgemm(const float* __restrict__ query,
                                                   const u8* __restrict__ E0t,
                                                   const u8* __restrict__ wvS,
                                                   const float* __restrict__ Rq,
                                                   u16* __restrict__ tout, int b0, int G)
{
    const int i = blockIdx.x;
    int bl, tile;
    if (G == 16) { bl = (i & 7) + 8 * (i >> 9); tile = (i >> 3) & 63; }
    else         { bl = i % G; tile = i / G; }
    const int b = b0 + bl;
    const int q0 = (tile >> 2) * 128, n0 = (tile & 3) * 128;
    const int tid = threadIdx.x, wv = tid >> 6, lane = tid & 63, l15 = lane & 15, g = lane >> 4;
    const int qg = wv >> 1, dg = wv & 1;

    __shared__ __align__(16) char As[16384], Bs[16384];

    const u8* Eb = E0t + (size_t)bl * LQ * LK;
    const u8* Vb = wvS + (size_t)b * DD * LK;

    // A: tiled source. chunk c = wv*4+p covers qt_local=c>>1, half=(c&1)
    const char* gAt = (const char*)Eb + (size_t)(q0 >> 4) * 128 * 256;
    // B: row-major + XOR swizzle
    const int srow = wv * 8 + (lane >> 3);
    const int scb = ((lane & 7) * 16) ^ ((srow & 7) << 4);
    const char* gB = (const char*)Vb + (size_t)(n0 + srow) * LK + scb;
    const size_t rstepB = (size_t)32 * LK;

    f32x4 z = {0.f, 0.f, 0.f, 0.f};
    f32x4 acc[4][4];
#pragma unroll
    for (int m = 0; m < 4; m++)
#pragma unroll
        for (int nf = 0; nf < 4; nf++) acc[m][nf] = z;

    auto stage = [&](int t) {
#pragma unroll
        for (int p = 0; p < 4; ++p) {
            int c = wv * 4 + p;
            gload16(gAt + ((size_t)(c >> 1) * 128 + t * 8) * 256 + (c & 1) * 1024 + lane * 16,
                    (char*)As + c * 1024);
            gload16(gB + p * rstepB + t * 128, (char*)Bs + p * 4096 + wv * 1024);
        }
    };
    stage(0);

    for (int t = 0; t < LK / 128; ++t) {
        __syncthreads();
        i64 af[4][4], bv[4][4];
#pragma unroll
        for (int m = 0; m < 4; m++) {
            // tiled read: qt_local = qg*4+m, row l15, kt16 = kk*2+(g>>1), half (g&1)
            const char* rp = (const char*)As + (qg * 4 + m) * 2048 + l15 * 16 + (g & 1) * 8;
#pragma unroll
            for (int kk = 0; kk < 4; kk++)
                af[m][kk] = *reinterpret_cast<const i64*>(rp + (kk * 2 + (g >> 1)) * 256);
        }
#pragma unroll
        for (int nf = 0; nf < 4; nf++) {
            int row = dg * 64 + nf * 16 + l15;
            const char* rp = (const char*)Bs + row * 128;
            int x = (row & 7) << 4;
#pragma unroll
            for (int kk = 0; kk < 4; kk++)
                bv[nf][kk] = *reinterpret_cast<const i64*>(rp + ((kk * 32 + g * 8) ^ x));
        }
        __syncthreads();
        if (t + 1 < LK / 128) stage(t + 1);
#pragma unroll
        for (int kk = 0; kk < 4; kk++)
#pragma unroll
            for (int nf = 0; nf < 4; nf++)
#pragma unroll
                for (int m = 0; m < 4; m++)
                    acc[m][nf] = MFMAF8(af[m][kk], bv[nf][kk], acc[m][nf]);
    }
#pragma unroll
    for (int m = 0; m < 4; m++) {
        float rqv[4];
#pragma unroll
        for (int j = 0; j < 4; j++)
            rqv[j] = Rq[(size_t)b * LQ + q0 + qg * 64 + m * 16 + g * 4 + j];
#pragma unroll
        for (int nf = 0; nf < 4; nf++)
#pragma unroll
            for (int j = 0; j < 4; j++) {
                int q = q0 + qg * 64 + m * 16 + g * 4 + j;
                int d = n0 + dg * 64 + nf * 16 + l15;
                size_t idx = ((size_t)q * BB + b) * DD + d;
                tout[idx] = f2bf(query[idx] - acc[m][nf][j] * rqv[j]);
            }
    }
}

// out = relu( t @ Wtb^T ): 128x128 tile, bf16 staged, K=512
__global__ __launch_bounds__(256, 3) void k_final(const u16* __restrict__ t, const u16* __restrict__ Wtb,
                                                  float* __restrict__ out)
{
    const int r0 = blockIdx.x * 128, n0 = blockIdx.y * 128;
    const int tid = threadIdx.x, wv = tid >> 6, lane = tid & 63, l15 = lane & 15, g = lane >> 4;
    const int qg = wv >> 1, dg = wv & 1;

    __shared__ __align__(16) u16 As[128 * 64], Bs[128 * 64];

    const int srow = wv * 8 + (lane >> 3);
    const int scb = ((lane & 7) * 16) ^ ((srow & 7) << 4);
    const char* gA = (const char*)(t + (size_t)(r0 + srow) * DD) + scb;
    const char* gB = (const char*)(Wtb + (size_t)(n0 + srow) * DD) + scb;
    const size_t rstep = (size_t)32 * DD * 2;

    f32x4 z = {0.f, 0.f, 0.f, 0.f};
    f32x4 acc[4][4];
#pragma unroll
    for (int m = 0; m < 4; m++)
#pragma unroll
        for (int nf = 0; nf < 4; nf++) acc[m][nf] = z;

#pragma unroll
    for (int p = 0; p < 4; ++p) {
        gload16(gA + p * rstep, (char*)As + p * 4096 + wv * 1024);
        gload16(gB + p * rstep, (char*)Bs + p * 4096 + wv * 1024);
    }

    for (int tt = 0; tt < DD / 64; ++tt) {
        __syncthreads();
        bf16x8 af[4][2], bv[4][2];
#pragma unroll
        for (int m = 0; m < 4; m++) {
            int row = qg * 64 + m * 16 + l15;
            const char* rp = (const char*)As + row * 128;
            int x = (row & 7) << 4;
#pragma unroll
            for (int kk = 0; kk < 2; kk++)
                af[m][kk] = *reinterpret_cast<const bf16x8*>(rp + ((kk * 64 + g * 16) ^ x));
        }
#pragma unroll
        for (int nf = 0; nf < 4; nf++) {
            int row = dg * 64 + nf * 16 + l15;
            const char* rp = (const char*)Bs + row * 128;
            int x = (row & 7) << 4;
#pragma unroll
            for (int kk = 0; kk < 2; kk++)
                bv[nf][kk] = *reinterpret_cast<const bf16x8*>(rp + ((kk * 64 + g * 16) ^ x));
        }
        __syncthreads();
        if (tt + 1 < DD / 64) {
            int ktb = (tt + 1) * 128;
#pragma unroll
            for (int p = 0; p < 4; ++p) {
                gload16(gA + p * rstep + ktb, (char*)As + p * 4096 + wv * 1024);
                gload16(gB + p * rstep + ktb, (char*)Bs + p * 4096 + wv * 1024);
            }
        }
#pragma unroll
        for (int nf = 0; nf < 4; nf++)
#pragma unroll
            for (int m = 0; m < 4; m++) {
                acc[m][nf] = MFMA16(af[m][0], bv[nf][0], acc[m][nf]);
                acc[m][nf] = MFMA16(af[m][1], bv[nf][1], acc[m][nf]);
            }
    }
#pragma unroll
    for (int m = 0; m < 4; m++)
#pragma unroll
        for (int nf = 0; nf < 4; nf++)
#pragma unroll
            for (int j = 0; j < 4; j++)
                out[(size_t)(r0 + qg * 64 + m * 16 + g * 4 + j) * DD + n0 + dg * 64 + nf * 16 + l15] =
                    fmaxf(acc[m][nf][j], 0.f);
}

extern "C" void kernel_launch(void* const* d_in, const int* in_sizes, int n_in,
                              void* d_out, int out_size, void* d_ws, size_t ws_size,
                              hipStream_t stream)
{
    const float* query = (const float*)d_in[0];
    const float* key   = (const float*)d_in[1];
    const float* value = (const float*)d_in[2];
    const float* WK    = (const float*)d_in[3];
    const float* WQ    = (const float*)d_in[4];
    const float* WV    = (const float*)d_in[5];
    const float* Wt    = (const float*)d_in[6];
    float* out = (float*)d_out;

    char* ws = (char*)d_ws;
    u16*   wqb = (u16*)(ws);                                   //  4 MB [B][LQ][64] bf16
    u16*   wkb = (u16*)(ws + (4u << 20));                      //  4 MB [B][LK][64] bf16
    u8*    wvS = (u8*)(ws + (8u << 20));                       // 16 MB [B][512][LK] fp8
    u16*   t   = (u16*)(ws + (24u << 20));                     // 32 MB [LQ][B][512] bf16
    u16*   vb  = (u16*)(ws + (56u << 20));                     // 32 MB [B][LK][512] bf16
    float* Rq  = (float*)(ws + (88u << 20));                   // 128 KB [B][LQ] f32
    float* ci  = (float*)(ws + (88u << 20) + (128u << 10));    // 128 KB [B][LK] f32
    u16*   WQb = (u16*)(ws + (88u << 20) + (256u << 10));      // 64 KB
    u16*   WKb = (u16*)(ws + (88u << 20) + (320u << 10));      // 64 KB
    u16*   WVb = (u16*)(ws + (88u << 20) + (384u << 10));      // 512 KB
    u16*   Wtb = (u16*)(ws + (88u << 20) + (896u << 10));      // 512 KB

    // per-group buffers: E0t (4MB/b) + Rpart (1MB/b) + Cpart (32KB/b)
    const size_t fixed = 90ull << 20;
    const size_t perG = (4ull << 20) + (1ull << 20) + (32ull << 10);
    int G = 0;
    for (int g = 16; g >= 1; g >>= 1)
        if (fixed + (size_t)g * perG <= ws_size) { G = g; break; }
    if (G == 0) G = 1;
    u8*    E0    = (u8*)(ws + fixed);
    float* Rpart = (float*)(ws + fixed + ((size_t)G << 22));
    float* Cpart = (float*)(ws + fixed + ((size_t)G << 22) + ((size_t)G << 20));

    k_cvt<<<32, 256, 0, stream>>>(WQ, WQb, DKK * DD);
    k_cvt<<<32, 256, 0, stream>>>(WK, WKb, DKK * DD);
    k_cvt<<<256, 256, 0, stream>>>(WV, WVb, DD * DD);
    k_cvt<<<256, 256, 0, stream>>>(Wt, Wtb, DD * DD);
    k_cvtv<<<8192, 256, 0, stream>>>(value, vb);

    k_projqk<<<dim3(LQ / 64, BB, 2), 256, 0, stream>>>(query, key, WQb, WKb, wqb, wkb);

    for (int b0 = 0; b0 < BB; b0 += G) {
        k_score<<<dim3(LK / 64, LQ / 512, G), 256, 0, stream>>>(wqb, wkb, E0, Rpart, b0);
        k_rsum<<<G * 8, 256, 0, stream>>>(Rpart, Rq, b0);
        k_colsum<<<dim3(32, 4, G), 256, 0, stream>>>(E0, Rq, Cpart, b0);
        k_csum<<<G * 8, 256, 0, stream>>>(Cpart, ci, b0);
        k_projv<<<dim3(LK / 128, DD / 128, G), 256, 0, stream>>>(vb, WVb, ci, wvS, b0);
        k_pvgemm<<<64 * G, 256, 0, stream>>>(query, E0, wvS, Rq, t, b0, G);
    }

    k_final<<<dim3(LQ * BB / 128, DD / 128), 256, 0, stream>>>(t, Wtb, out);
}

// Round 13
// 275.958 us; speedup vs baseline: 1.1003x; 1.1003x over previous
//
#include <hip/hip_runtime.h>

#define LQ 2048
#define LK 2048
#define BB 16
#define DD 512
#define DKK 64
#define EPSF 1e-9f

typedef unsigned short u16;
typedef unsigned char u8;
typedef long i64;
typedef __attribute__((ext_vector_type(8))) short bf16x8;
typedef __attribute__((ext_vector_type(4))) float f32x4;
#define MFMA16(a, b, c) __builtin_amdgcn_mfma_f32_16x16x32_bf16(a, b, c, 0, 0, 0)
#define MFMAF8(a, b, c) __builtin_amdgcn_mfma_f32_16x16x32_fp8_fp8(a, b, c, 0, 0, 0)

__device__ inline u16 f2bf(float f) {
    unsigned int u = __float_as_uint(f);
    u += 0x7fffu + ((u >> 16) & 1u);   // RNE
    return (u16)(u >> 16);
}
__device__ inline bf16x8 cvt8(float4 a, float4 b) {
    bf16x8 r;
    r[0] = (short)f2bf(a.x); r[1] = (short)f2bf(a.y); r[2] = (short)f2bf(a.z); r[3] = (short)f2bf(a.w);
    r[4] = (short)f2bf(b.x); r[5] = (short)f2bf(b.y); r[6] = (short)f2bf(b.z); r[7] = (short)f2bf(b.w);
    return r;
}
__device__ inline int pk_fp8x4(float a, float b, float c, float d) {
    int r = __builtin_amdgcn_cvt_pk_fp8_f32(a, b, 0, false);
    r = __builtin_amdgcn_cvt_pk_fp8_f32(c, d, r, true);
    return r;
}
__device__ inline void gload16(const void* g, void* l) {
    __builtin_amdgcn_global_load_lds((const __attribute__((address_space(1))) unsigned int*)g,
                                     (__attribute__((address_space(3))) unsigned int*)l, 16, 0, 0);
}

__global__ __launch_bounds__(256) void k_cvt(const float* __restrict__ src, u16* __restrict__ dst, int n) {
    int i = (blockIdx.x * 256 + threadIdx.x) * 4;
    if (i < n) {
        float4 v = *reinterpret_cast<const float4*>(src + i);
        *reinterpret_cast<ushort4*>(dst + i) = make_ushort4(f2bf(v.x), f2bf(v.y), f2bf(v.z), f2bf(v.w));
    }
}

// value f32 [LK][B][D] -> vb bf16 [B][LK][D]
__global__ __launch_bounds__(256) void k_cvtv(const float* __restrict__ value, u16* __restrict__ vb) {
    size_t i = ((size_t)blockIdx.x * 256 + threadIdx.x) * 8;
    int k = (int)(i >> 13);
    int r = (int)(i & 8191);
    int b = r >> 9, d = r & 511;
    float4 a = *reinterpret_cast<const float4*>(value + i);
    float4 c = *reinterpret_cast<const float4*>(value + i + 4);
    *reinterpret_cast<bf16x8*>(vb + ((size_t)b * LK + k) * DD + d) = cvt8(a, c);
}

// fused q/k projection + l2norm
__global__ __launch_bounds__(256) void k_projqk(const float* __restrict__ xq, const float* __restrict__ xk,
                                                const u16* __restrict__ Wq, const u16* __restrict__ Wk,
                                                u16* __restrict__ yq, u16* __restrict__ yk)
{
    const float* x = blockIdx.z ? xk : xq;
    const u16* Wb = blockIdx.z ? Wk : Wq;
    u16* y = blockIdx.z ? yk : yq;
    const int b = blockIdx.y, r0 = blockIdx.x * 64;
    const int tid = threadIdx.x, wave = tid >> 6, lane = tid & 63, l15 = lane & 15, g = lane >> 4;
    const int rw = r0 + wave * 16;
    f32x4 z = {0.f, 0.f, 0.f, 0.f};
    f32x4 acc[4];
#pragma unroll
    for (int nf = 0; nf < 4; nf++) acc[nf] = z;

    for (int kt = 0; kt < DD; kt += 32) {
        const float* p = x + ((size_t)(rw + l15) * BB + b) * DD + kt + g * 8;
        bf16x8 af = cvt8(*reinterpret_cast<const float4*>(p), *reinterpret_cast<const float4*>(p + 4));
#pragma unroll
        for (int nf = 0; nf < 4; nf++) {
            bf16x8 bf_ = *reinterpret_cast<const bf16x8*>(Wb + (size_t)(nf * 16 + l15) * DD + kt + g * 8);
            acc[nf] = MFMA16(af, bf_, acc[nf]);
        }
    }
    float rn[4];
#pragma unroll
    for (int j = 0; j < 4; j++) {
        float t2 = acc[0][j] * acc[0][j] + acc[1][j] * acc[1][j]
                 + acc[2][j] * acc[2][j] + acc[3][j] * acc[3][j];
        t2 += __shfl_xor(t2, 1, 64);
        t2 += __shfl_xor(t2, 2, 64);
        t2 += __shfl_xor(t2, 4, 64);
        t2 += __shfl_xor(t2, 8, 64);
        rn[j] = 1.f / fmaxf(sqrtf(t2), 1e-12f);
    }
#pragma unroll
    for (int nf = 0; nf < 4; nf++)
#pragma unroll
        for (int j = 0; j < 4; j++) {
            int q = rw + g * 4 + j;
            y[((size_t)b * LQ + q) * DKK + nf * 16 + l15] = f2bf(acc[nf][j] * rn[j]);
        }
}

// Single QK^T pass, TILED E0 output. Each wave owns TWO k-tiles: one Q-frag pair feeds
// 4 MFMAs (2x ILP), Q read volume through L2 halves. Prefetch pinned by sched_barrier.
// E0t layout: [qt][kt][16q][16k] bytes, tile = 256B.
// Rpart[bl][kt][q] = per-k-tile row sums.  grid (LK/128, LQ/512, G)
__global__ __launch_bounds__(256) void k_score(const u16* __restrict__ wqb, const u16* __restrict__ wkb,
                                               u8* __restrict__ E0t, float* __restrict__ Rpart, int b0)
{
    const int bx = blockIdx.x, qc = blockIdx.y, bl = blockIdx.z, b = b0 + bl;
    const int tid = threadIdx.x, w = tid >> 6, lane = tid & 63, l15 = lane & 15, g = lane >> 4;
    const int kt0 = bx * 8 + w * 2;          // this wave's first k-tile (owns kt0, kt0+1)
    f32x4 z = {0.f, 0.f, 0.f, 0.f};

    bf16x8 af[2][2];
#pragma unroll
    for (int j = 0; j < 2; j++) {
        const u16* ar = wkb + ((size_t)b * LK + (kt0 + j) * 16 + l15) * DKK;
        af[j][0] = *reinterpret_cast<const bf16x8*>(ar + g * 8);
        af[j][1] = *reinterpret_cast<const bf16x8*>(ar + 32 + g * 8);
    }
    u8* Eb = E0t + (size_t)bl * LQ * LK + l15 * 16 + g * 4;
    float* Rp0 = Rpart + ((size_t)bl * 128 + kt0) * LQ + qc * 512;
    float* Rp1 = Rp0 + LQ;
    const u16* qbase = wqb + ((size_t)b * LQ + qc * 512 + l15) * DKK + g * 8;

    bf16x8 c0 = *reinterpret_cast<const bf16x8*>(qbase);
    bf16x8 c1 = *reinterpret_cast<const bf16x8*>(qbase + 32);
    bf16x8 n0_ = c0, n1_ = c1;

#pragma unroll 4
    for (int qf = 0; qf < 32; qf++) {
        if (qf < 31) {
            const u16* br = qbase + (size_t)(qf + 1) * 16 * DKK;
            n0_ = *reinterpret_cast<const bf16x8*>(br);
            n1_ = *reinterpret_cast<const bf16x8*>(br + 32);
        }
        __builtin_amdgcn_sched_barrier(0);   // pin prefetch issue above compute
        int qt = qc * 32 + qf;
#pragma unroll
        for (int j = 0; j < 2; j++) {
            f32x4 s = z;
            s = MFMA16(af[j][0], c0, s);
            s = MFMA16(af[j][1], c1, s);
            float pe0 = __expf(s[0]), pe1 = __expf(s[1]);
            float pe2 = __expf(s[2]), pe3 = __expf(s[3]);
            *reinterpret_cast<int*>(Eb + ((size_t)qt * 128 + kt0 + j) * 256) =
                pk_fp8x4(pe0, pe1, pe2, pe3);
            float v = pe0 + pe1 + pe2 + pe3;
            v += __shfl_xor(v, 16, 64);
            v += __shfl_xor(v, 32, 64);
            if (g == 0) (j ? Rp1 : Rp0)[qf * 16 + l15] = v;
        }
        c0 = n0_; c1 = n1_;
    }
}

// Rq[b][q] = 1 / sum_p Rpart[bl][p][q]
__global__ __launch_bounds__(256) void k_rsum(const float* __restrict__ Rpart, float* __restrict__ Rq, int b0) {
    int idx = blockIdx.x * 256 + threadIdx.x;
    int bl = idx >> 11, q = idx & 2047;
    const float* rp = Rpart + (size_t)bl * 128 * LQ + q;
    float s = 0.f;
    for (int p = 0; p < 128; p++) s += rp[(size_t)p * LQ];
    Rq[(size_t)(b0 + bl) * LQ + q] = 1.f / s;
}

// Cpart[bl][qc][k] = sum over 512 q (32 qt) of E0t[qt][kt]*Rq.  grid (32, 4, G)
__global__ __launch_bounds__(256) void k_colsum(const u8* __restrict__ E0t, const float* __restrict__ Rq,
                                                float* __restrict__ Cpart, int b0)
{
    const int qc = blockIdx.y, bl = blockIdx.z;
    const int tid = threadIdx.x, w = tid >> 6, lane = tid & 63, l15 = lane & 15, g = lane >> 4;
    const int kt = blockIdx.x * 4 + w;
    const u8* base = E0t + (size_t)bl * LQ * LK + (size_t)kt * 256 + l15 * 16 + g * 4;
    const float* rq = Rq + (size_t)(b0 + bl) * LQ;
    float acc[4] = {0.f, 0.f, 0.f, 0.f};
#pragma unroll 4
    for (int i = 0; i < 32; i++) {
        int qt = qc * 32 + i;
        unsigned int u = *reinterpret_cast<const unsigned int*>(base + (size_t)qt * 32768);
        float wgt = rq[qt * 16 + l15];
#pragma unroll
        for (int by = 0; by < 4; by++) {
            // e4m3fn -> f32 for positive normals (E0 in [0.37, 2.72])
            unsigned int f = 0x3C000000u + (((u >> (8 * by)) & 0x7Fu) << 20);
            acc[by] += __uint_as_float(f) * wgt;
        }
    }
#pragma unroll
    for (int by = 0; by < 4; by++) {
        acc[by] += __shfl_xor(acc[by], 1, 64);
        acc[by] += __shfl_xor(acc[by], 2, 64);
        acc[by] += __shfl_xor(acc[by], 4, 64);
        acc[by] += __shfl_xor(acc[by], 8, 64);
    }
    if (l15 == 0) {
        float4 v4 = make_float4(acc[0], acc[1], acc[2], acc[3]);
        *reinterpret_cast<float4*>(Cpart + ((size_t)bl * 4 + qc) * LK + kt * 16 + g * 4) = v4;
    }
}

// ci[b][k] = 1/(eps + sum_qc Cpart)
__global__ __launch_bounds__(256) void k_csum(const float* __restrict__ Cpart, float* __restrict__ ci, int b0) {
    int idx = blockIdx.x * 256 + threadIdx.x;
    int bl = idx >> 11, k = idx & 2047;
    const float* cp = Cpart + (size_t)bl * 4 * LK + k;
    float s = 0.f;
#pragma unroll
    for (int p = 0; p < 4; p++) s += cp[(size_t)p * LK];
    ci[(size_t)(b0 + bl) * LK + k] = 1.f / (EPSF + s);
}

// wvS[b][d][k] = fp8( (vb[b][k,:] @ WVb[d,:]) * ci[b][k] )  -- staged GEMM
__global__ __launch_bounds__(256, 3) void k_projv(const u16* __restrict__ vb, const u16* __restrict__ WVb,
                                                  const float* __restrict__ ci, u8* __restrict__ wvS, int b0)
{
    const int b = b0 + blockIdx.z, k0 = blockIdx.x * 128, n0 = blockIdx.y * 128;
    const int tid = threadIdx.x, wv = tid >> 6, lane = tid & 63, l15 = lane & 15, g = lane >> 4;
    const int qg = wv >> 1, dg = wv & 1;

    __shared__ __align__(16) u16 As[128 * 64], Bs[128 * 64];

    const int srow = wv * 8 + (lane >> 3);
    const int scb = ((lane & 7) * 16) ^ ((srow & 7) << 4);
    const char* gA = (const char*)(vb + ((size_t)b * LK + k0 + srow) * DD) + scb;
    const char* gB = (const char*)(WVb + (size_t)(n0 + srow) * DD) + scb;
    const size_t rstep = (size_t)32 * DD * 2;

    f32x4 z = {0.f, 0.f, 0.f, 0.f};
    f32x4 acc[4][4];
#pragma unroll
    for (int m = 0; m < 4; m++)
#pragma unroll
        for (int nf = 0; nf < 4; nf++) acc[m][nf] = z;

#pragma unroll
    for (int p = 0; p < 4; ++p) {
        gload16(gA + p * rstep, (char*)As + p * 4096 + wv * 1024);
        gload16(gB + p * rstep, (char*)Bs + p * 4096 + wv * 1024);
    }

    for (int tt = 0; tt < DD / 64; ++tt) {
        __syncthreads();
        bf16x8 af[4][2], bv[4][2];
#pragma unroll
        for (int m = 0; m < 4; m++) {
            int row = qg * 64 + m * 16 + l15;
            const char* rp = (const char*)As + row * 128;
            int x = (row & 7) << 4;
#pragma unroll
            for (int kk = 0; kk < 2; kk++)
                af[m][kk] = *reinterpret_cast<const bf16x8*>(rp + ((kk * 64 + g * 16) ^ x));
        }
#pragma unroll
        for (int nf = 0; nf < 4; nf++) {
            int row = dg * 64 + nf * 16 + l15;
            const char* rp = (const char*)Bs + row * 128;
            int x = (row & 7) << 4;
#pragma unroll
            for (int kk = 0; kk < 2; kk++)
                bv[nf][kk] = *reinterpret_cast<const bf16x8*>(rp + ((kk * 64 + g * 16) ^ x));
        }
        __syncthreads();
        if (tt + 1 < DD / 64) {
            int ktb = (tt + 1) * 128;
#pragma unroll
            for (int p = 0; p < 4; ++p) {
                gload16(gA + p * rstep + ktb, (char*)As + p * 4096 + wv * 1024);
                gload16(gB + p * rstep + ktb, (char*)Bs + p * 4096 + wv * 1024);
            }
        }
#pragma unroll
        for (int nf = 0; nf < 4; nf++)
#pragma unroll
            for (int m = 0; m < 4; m++) {
                acc[m][nf] = MFMA16(af[m][0], bv[nf][0], acc[m][nf]);
                acc[m][nf] = MFMA16(af[m][1], bv[nf][1], acc[m][nf]);
            }
    }
#pragma unroll
    for (int m = 0; m < 4; m++) {
        float cv[4];
        int kb = k0 + qg * 64 + m * 16 + g * 4;
#pragma unroll
        for (int j = 0; j < 4; j++) cv[j] = ci[(size_t)b * LK + kb + j];
#pragma unroll
        for (int nf = 0; nf < 4; nf++) {
            int d = n0 + dg * 64 + nf * 16 + l15;
            *reinterpret_cast<int*>(wvS + ((size_t)b * DD + d) * LK + kb) =
                pk_fp8x4(acc[m][nf][0] * cv[0], acc[m][nf][1] * cv[1],
                         acc[m][nf][2] * cv[2], acc[m][nf][3] * cv[3]);
        }
    }
}

// t[q,b,:] = query - Rq[q] * (E0t @ wvS^T).  fp8 GEMM, BK=128.
// A (E0t) is tiled [qt][kt][16][16]: staged as 8 contiguous 2KB runs, LDS linear.
__global__ __launch_bounds__(256, 3) void k_pvgemm(const float* __restrict__ query,
                                                   const u8* __restrict__ E0t,
                                                   const u8* __restrict__ wvS,
                                                   const float* __restrict__ Rq,
                                                   u16* __restrict__ tout, int b0, int G)
{
    const int i = blockIdx.x;
    int bl, tile;
    if (G == 16) { bl = (i & 7) + 8 * (i >> 9); tile = (i >> 3) & 63; }
    else         { bl = i % G; tile = i / G; }
    const int b = b0 + bl;
    const int q0 = (tile >> 2) * 128, n0 = (tile & 3) * 128;
    const int tid = threadIdx.x, wv = tid >> 6, lane = tid & 63, l15 = lane & 15, g = lane >> 4;
    const int qg = wv >> 1, dg = wv & 1;

    __shared__ __align__(16) char As[16384], Bs[16384];

    const u8* Eb = E0t + (size_t)bl * LQ * LK;
    const u8* Vb = wvS + (size_t)b * DD * LK;

    // A: tiled source. chunk c = wv*4+p covers qt_local=c>>1, half=(c&1)
    const char* gAt = (const char*)Eb + (size_t)(q0 >> 4) * 128 * 256;
    // B: row-major + XOR swizzle
    const int srow = wv * 8 + (lane >> 3);
    const int scb = ((lane & 7) * 16) ^ ((srow & 7) << 4);
    const char* gB = (const char*)Vb + (size_t)(n0 + srow) * LK + scb;
    const size_t rstepB = (size_t)32 * LK;

    f32x4 z = {0.f, 0.f, 0.f, 0.f};
    f32x4 acc[4][4];
#pragma unroll
    for (int m = 0; m < 4; m++)
#pragma unroll
        for (int nf = 0; nf < 4; nf++) acc[m][nf] = z;

    auto stage = [&](int t) {
#pragma unroll
        for (int p = 0; p < 4; ++p) {
            int c = wv * 4 + p;
            gload16(gAt + ((size_t)(c >> 1) * 128 + t * 8) * 256 + (c & 1) * 1024 + lane * 16,
                    (char*)As + c * 1024);
            gload16(gB + p * rstepB + t * 128, (char*)Bs + p * 4096 + wv * 1024);
        }
    };
    stage(0);

    for (int t = 0; t < LK / 128; ++t) {
        __syncthreads();
        i64 af[4][4], bv[4][4];
#pragma unroll
        for (int m = 0; m < 4; m++) {
            // tiled read: qt_local = qg*4+m, row l15, kt16 = kk*2+(g>>1), half (g&1)
            const char* rp = (const char*)As + (qg * 4 + m) * 2048 + l15 * 16 + (g & 1) * 8;
#pragma unroll
            for (int kk = 0; kk < 4; kk++)
                af[m][kk] = *reinterpret_cast<const i64*>(rp + (kk * 2 + (g >> 1)) * 256);
        }
#pragma unroll
        for (int nf = 0; nf < 4; nf++) {
            int row = dg * 64 + nf * 16 + l15;
            const char* rp = (const char*)Bs + row * 128;
            int x = (row & 7) << 4;
#pragma unroll
            for (int kk = 0; kk < 4; kk++)
                bv[nf][kk] = *reinterpret_cast<const i64*>(rp + ((kk * 32 + g * 8) ^ x));
        }
        __syncthreads();
        if (t + 1 < LK / 128) stage(t + 1);
#pragma unroll
        for (int kk = 0; kk < 4; kk++)
#pragma unroll
            for (int nf = 0; nf < 4; nf++)
#pragma unroll
                for (int m = 0; m < 4; m++)
                    acc[m][nf] = MFMAF8(af[m][kk], bv[nf][kk], acc[m][nf]);
    }
#pragma unroll
    for (int m = 0; m < 4; m++) {
        float rqv[4];
#pragma unroll
        for (int j = 0; j < 4; j++)
            rqv[j] = Rq[(size_t)b * LQ + q0 + qg * 64 + m * 16 + g * 4 + j];
#pragma unroll
        for (int nf = 0; nf < 4; nf++)
#pragma unroll
            for (int j = 0; j < 4; j++) {
                int q = q0 + qg * 64 + m * 16 + g * 4 + j;
                int d = n0 + dg * 64 + nf * 16 + l15;
                size_t idx = ((size_t)q * BB + b) * DD + d;
                tout[idx] = f2bf(query[idx] - acc[m][nf][j] * rqv[j]);
            }
    }
}

// out = relu( t @ Wtb^T ): 128x128 tile, bf16 staged, K=512
__global__ __launch_bounds__(256, 3) void k_final(const u16* __restrict__ t, const u16* __restrict__ Wtb,
                                                  float* __restrict__ out)
{
    const int r0 = blockIdx.x * 128, n0 = blockIdx.y * 128;
    const int tid = threadIdx.x, wv = tid >> 6, lane = tid & 63, l15 = lane & 15, g = lane >> 4;
    const int qg = wv >> 1, dg = wv & 1;

    __shared__ __align__(16) u16 As[128 * 64], Bs[128 * 64];

    const int srow = wv * 8 + (lane >> 3);
    const int scb = ((lane & 7) * 16) ^ ((srow & 7) << 4);
    const char* gA = (const char*)(t + (size_t)(r0 + srow) * DD) + scb;
    const char* gB = (const char*)(Wtb + (size_t)(n0 + srow) * DD) + scb;
    const size_t rstep = (size_t)32 * DD * 2;

    f32x4 z = {0.f, 0.f, 0.f, 0.f};
    f32x4 acc[4][4];
#pragma unroll
    for (int m = 0; m < 4; m++)
#pragma unroll
        for (int nf = 0; nf < 4; nf++) acc[m][nf] = z;

#pragma unroll
    for (int p = 0; p < 4; ++p) {
        gload16(gA + p * rstep, (char*)As + p * 4096 + wv * 1024);
        gload16(gB + p * rstep, (char*)Bs + p * 4096 + wv * 1024);
    }

    for (int tt = 0; tt < DD / 64; ++tt) {
        __syncthreads();
        bf16x8 af[4][2], bv[4][2];
#pragma unroll
        for (int m = 0; m < 4; m++) {
            int row = qg * 64 + m * 16 + l15;
            const char* rp = (const char*)As + row * 128;
            int x = (row & 7) << 4;
#pragma unroll
            for (int kk = 0; kk < 2; kk++)
                af[m][kk] = *reinterpret_cast<const bf16x8*>(rp + ((kk * 64 + g * 16) ^ x));
        }
#pragma unroll
        for (int nf = 0; nf < 4; nf++) {
            int row = dg * 64 + nf * 16 + l15;
            const char* rp = (const char*)Bs + row * 128;
            int x = (row & 7) << 4;
#pragma unroll
            for (int kk = 0; kk < 2; kk++)
                bv[nf][kk] = *reinterpret_cast<const bf16x8*>(rp + ((kk * 64 + g * 16) ^ x));
        }
        __syncthreads();
        if (tt + 1 < DD / 64) {
            int ktb = (tt + 1) * 128;
#pragma unroll
            for (int p = 0; p < 4; ++p) {
                gload16(gA + p * rstep + ktb, (char*)As + p * 4096 + wv * 1024);
                gload16(gB + p * rstep + ktb, (char*)Bs + p * 4096 + wv * 1024);
            }
        }
#pragma unroll
        for (int nf = 0; nf < 4; nf++)
#pragma unroll
            for (int m = 0; m < 4; m++) {
                acc[m][nf] = MFMA16(af[m][0], bv[nf][0], acc[m][nf]);
                acc[m][nf] = MFMA16(af[m][1], bv[nf][1], acc[m][nf]);
            }
    }
#pragma unroll
    for (int m = 0; m < 4; m++)
#pragma unroll
        for (int nf = 0; nf < 4; nf++)
#pragma unroll
            for (int j = 0; j < 4; j++)
                out[(size_t)(r0 + qg * 64 + m * 16 + g * 4 + j) * DD + n0 + dg * 64 + nf * 16 + l15] =
                    fmaxf(acc[m][nf][j], 0.f);
}

extern "C" void kernel_launch(void* const* d_in, const int* in_sizes, int n_in,
                              void* d_out, int out_size, void* d_ws, size_t ws_size,
                              hipStream_t stream)
{
    const float* query = (const float*)d_in[0];
    const float* key   = (const float*)d_in[1];
    const float* value = (const float*)d_in[2];
    const float* WK    = (const float*)d_in[3];
    const float* WQ    = (const float*)d_in[4];
    const float* WV    = (const float*)d_in[5];
    const float* Wt    = (const float*)d_in[6];
    float* out = (float*)d_out;

    char* ws = (char*)d_ws;
    u16*   wqb = (u16*)(ws);                                   //  4 MB [B][LQ][64] bf16
    u16*   wkb = (u16*)(ws + (4u << 20));                      //  4 MB [B][LK][64] bf16
    u8*    wvS = (u8*)(ws + (8u << 20));                       // 16 MB [B][512][LK] fp8
    u16*   t   = (u16*)(ws + (24u << 20));                     // 32 MB [LQ][B][512] bf16
    u16*   vb  = (u16*)(ws + (56u << 20));                     // 32 MB [B][LK][512] bf16
    float* Rq  = (float*)(ws + (88u << 20));                   // 128 KB [B][LQ] f32
    float* ci  = (float*)(ws + (88u << 20) + (128u << 10));    // 128 KB [B][LK] f32
    u16*   WQb = (u16*)(ws + (88u << 20) + (256u << 10));      // 64 KB
    u16*   WKb = (u16*)(ws + (88u << 20) + (320u << 10));      // 64 KB
    u16*   WVb = (u16*)(ws + (88u << 20) + (384u << 10));      // 512 KB
    u16*   Wtb = (u16*)(ws + (88u << 20) + (896u << 10));      // 512 KB

    // per-group buffers: E0t (4MB/b) + Rpart (1MB/b) + Cpart (32KB/b)
    const size_t fixed = 90ull << 20;
    const size_t perG = (4ull << 20) + (1ull << 20) + (32ull << 10);
    int G = 0;
    for (int g = 16; g >= 1; g >>= 1)
        if (fixed + (size_t)g * perG <= ws_size) { G = g; break; }
    if (G == 0) G = 1;
    u8*    E0    = (u8*)(ws + fixed);
    float* Rpart = (float*)(ws + fixed + ((size_t)G << 22));
    float* Cpart = (float*)(ws + fixed + ((size_t)G << 22) + ((size_t)G << 20));

    k_cvt<<<32, 256, 0, stream>>>(WQ, WQb, DKK * DD);
    k_cvt<<<32, 256, 0, stream>>>(WK, WKb, DKK * DD);
    k_cvt<<<256, 256, 0, stream>>>(WV, WVb, DD * DD);
    k_cvt<<<256, 256, 0, stream>>>(Wt, Wtb, DD * DD);
    k_cvtv<<<8192, 256, 0, stream>>>(value, vb);

    k_projqk<<<dim3(LQ / 64, BB, 2), 256, 0, stream>>>(query, key, WQb, WKb, wqb, wkb);

    for (int b0 = 0; b0 < BB; b0 += G) {
        k_score<<<dim3(LK / 128, LQ / 512, G), 256, 0, stream>>>(wqb, wkb, E0, Rpart, b0);
        k_rsum<<<G * 8, 256, 0, stream>>>(Rpart, Rq, b0);
        k_colsum<<<dim3(32, 4, G), 256, 0, stream>>>(E0, Rq, Cpart, b0);
        k_csum<<<G * 8, 256, 0, stream>>>(Cpart, ci, b0);
        k_projv<<<dim3(LK / 128, DD / 128, G), 256, 0, stream>>>(vb, WVb, ci, wvS, b0);
        k_pvgemm<<<64 * G, 256, 0, stream>>>(query, E0, wvS, Rq, t, b0, G);
    }

    k_final<<<dim3(LQ * BB / 128, DD / 128), 256, 0, stream>>>(t, Wtb, out);
}

// Round 14
// 257.936 us; speedup vs baseline: 1.1772x; 1.0699x over previous
//
#include <hip/hip_runtime.h>

#define LQ 2048
#define LK 2048
#define BB 16
#define DD 512
#define DKK 64
#define EPSF 1e-9f

typedef unsigned short u16;
typedef unsigned char u8;
typedef long i64;
typedef __attribute__((ext_vector_type(8))) short bf16x8;
typedef __attribute__((ext_vector_type(4))) float f32x4;
#define MFMA16(a, b, c) __builtin_amdgcn_mfma_f32_16x16x32_bf16(a, b, c, 0, 0, 0)
#define MFMAF8(a, b, c) __builtin_amdgcn_mfma_f32_16x16x32_fp8_fp8(a, b, c, 0, 0, 0)

__device__ inline u16 f2bf(float f) {
    unsigned int u = __float_as_uint(f);
    u += 0x7fffu + ((u >> 16) & 1u);   // RNE
    return (u16)(u >> 16);
}
__device__ inline bf16x8 cvt8(float4 a, float4 b) {
    bf16x8 r;
    r[0] = (short)f2bf(a.x); r[1] = (short)f2bf(a.y); r[2] = (short)f2bf(a.z); r[3] = (short)f2bf(a.w);
    r[4] = (short)f2bf(b.x); r[5] = (short)f2bf(b.y); r[6] = (short)f2bf(b.z); r[7] = (short)f2bf(b.w);
    return r;
}
__device__ inline int pk_fp8x4(float a, float b, float c, float d) {
    int r = __builtin_amdgcn_cvt_pk_fp8_f32(a, b, 0, false);
    r = __builtin_amdgcn_cvt_pk_fp8_f32(c, d, r, true);
    return r;
}
__device__ inline void gload16(const void* g, void* l) {
    __builtin_amdgcn_global_load_lds((const __attribute__((address_space(1))) unsigned int*)g,
                                     (__attribute__((address_space(3))) unsigned int*)l, 16, 0, 0);
}

__global__ __launch_bounds__(256) void k_cvt(const float* __restrict__ src, u16* __restrict__ dst, int n) {
    int i = (blockIdx.x * 256 + threadIdx.x) * 4;
    if (i < n) {
        float4 v = *reinterpret_cast<const float4*>(src + i);
        *reinterpret_cast<ushort4*>(dst + i) = make_ushort4(f2bf(v.x), f2bf(v.y), f2bf(v.z), f2bf(v.w));
    }
}

// fused q/k projection + l2norm.  Staged-async: A (f32, strided rows) gather-staged into
// LDS dbuf via per-lane-source global_load_lds + XOR swizzle; cvt on read; B direct (L2).
// Block: 128 rows, 4 waves (32 rows each).  grid (LQ/128, BB, 2)
__global__ __launch_bounds__(256) void k_projqk(const float* __restrict__ xq, const float* __restrict__ xk,
                                                const u16* __restrict__ Wq, const u16* __restrict__ Wk,
                                                u16* __restrict__ yq, u16* __restrict__ yk)
{
    const float* x = blockIdx.z ? xk : xq;
    const u16* Wb = blockIdx.z ? Wk : Wq;
    u16* y = blockIdx.z ? yk : yq;
    const int b = blockIdx.y, r0 = blockIdx.x * 128;
    const int tid = threadIdx.x, wv = tid >> 6, lane = tid & 63, l15 = lane & 15, g = lane >> 4;

    __shared__ __align__(16) float As[2][128 * 32];   // 2 x 16 KB

    const int srow = wv * 8 + (lane >> 3);
    const int scb = ((lane & 7) * 16) ^ ((srow & 7) << 4);

    f32x4 z = {0.f, 0.f, 0.f, 0.f};
    f32x4 acc[2][4];
#pragma unroll
    for (int m = 0; m < 2; m++)
#pragma unroll
        for (int nf = 0; nf < 4; nf++) acc[m][nf] = z;

    auto stage = [&](int buf, int kt) {
#pragma unroll
        for (int p = 0; p < 4; ++p) {
            const char* src = (const char*)(x + ((size_t)(r0 + p * 32 + srow) * BB + b) * DD) + kt * 4 + scb;
            gload16(src, (char*)As[buf] + p * 4096 + wv * 1024);
        }
    };
    stage(0, 0);
    int buf = 0;
    for (int tt = 0; tt < 16; ++tt) {
        __syncthreads();                       // buf landed; prior readers of buf^1 done
        if (tt + 1 < 16) stage(buf ^ 1, (tt + 1) * 32);
        bf16x8 af[2];
#pragma unroll
        for (int m = 0; m < 2; m++) {
            int row = wv * 32 + m * 16 + l15;
            const char* rp = (const char*)As[buf] + row * 128;
            int xs = (row & 7) << 4;
            float4 fa = *reinterpret_cast<const float4*>(rp + ((g * 32) ^ xs));
            float4 fb = *reinterpret_cast<const float4*>(rp + ((g * 32 + 16) ^ xs));
            af[m] = cvt8(fa, fb);
        }
#pragma unroll
        for (int nf = 0; nf < 4; nf++) {
            bf16x8 bw = *reinterpret_cast<const bf16x8*>(Wb + (size_t)(nf * 16 + l15) * DD + tt * 32 + g * 8);
            acc[0][nf] = MFMA16(af[0], bw, acc[0][nf]);
            acc[1][nf] = MFMA16(af[1], bw, acc[1][nf]);
        }
        buf ^= 1;
    }
#pragma unroll
    for (int m = 0; m < 2; m++) {
        float rn[4];
#pragma unroll
        for (int j = 0; j < 4; j++) {
            float t2 = acc[m][0][j] * acc[m][0][j] + acc[m][1][j] * acc[m][1][j]
                     + acc[m][2][j] * acc[m][2][j] + acc[m][3][j] * acc[m][3][j];
            t2 += __shfl_xor(t2, 1, 64);
            t2 += __shfl_xor(t2, 2, 64);
            t2 += __shfl_xor(t2, 4, 64);
            t2 += __shfl_xor(t2, 8, 64);
            rn[j] = 1.f / fmaxf(sqrtf(t2), 1e-12f);
        }
#pragma unroll
        for (int nf = 0; nf < 4; nf++)
#pragma unroll
            for (int j = 0; j < 4; j++) {
                int q = r0 + wv * 32 + m * 16 + g * 4 + j;
                y[((size_t)b * LQ + q) * DKK + nf * 16 + l15] = f2bf(acc[m][nf][j] * rn[j]);
            }
    }
}

// Single QK^T pass, TILED E0 output. Each wave owns TWO k-tiles (2x MFMA ILP per Q-frag).
// E0t layout: [qt][kt][16q][16k] bytes, tile = 256B.
// Rpart[bl][kt][q] = per-k-tile row sums.  grid (LK/128, LQ/512, G)
__global__ __launch_bounds__(256) void k_score(const u16* __restrict__ wqb, const u16* __restrict__ wkb,
                                               u8* __restrict__ E0t, float* __restrict__ Rpart, int b0)
{
    const int bx = blockIdx.x, qc = blockIdx.y, bl = blockIdx.z, b = b0 + bl;
    const int tid = threadIdx.x, w = tid >> 6, lane = tid & 63, l15 = lane & 15, g = lane >> 4;
    const int kt0 = bx * 8 + w * 2;
    f32x4 z = {0.f, 0.f, 0.f, 0.f};

    bf16x8 af[2][2];
#pragma unroll
    for (int j = 0; j < 2; j++) {
        const u16* ar = wkb + ((size_t)b * LK + (kt0 + j) * 16 + l15) * DKK;
        af[j][0] = *reinterpret_cast<const bf16x8*>(ar + g * 8);
        af[j][1] = *reinterpret_cast<const bf16x8*>(ar + 32 + g * 8);
    }
    u8* Eb = E0t + (size_t)bl * LQ * LK + l15 * 16 + g * 4;
    float* Rp0 = Rpart + ((size_t)bl * 128 + kt0) * LQ + qc * 512;
    float* Rp1 = Rp0 + LQ;
    const u16* qbase = wqb + ((size_t)b * LQ + qc * 512 + l15) * DKK + g * 8;

    bf16x8 c0 = *reinterpret_cast<const bf16x8*>(qbase);
    bf16x8 c1 = *reinterpret_cast<const bf16x8*>(qbase + 32);
    bf16x8 n0_ = c0, n1_ = c1;

#pragma unroll 4
    for (int qf = 0; qf < 32; qf++) {
        if (qf < 31) {
            const u16* br = qbase + (size_t)(qf + 1) * 16 * DKK;
            n0_ = *reinterpret_cast<const bf16x8*>(br);
            n1_ = *reinterpret_cast<const bf16x8*>(br + 32);
        }
        __builtin_amdgcn_sched_barrier(0);
        int qt = qc * 32 + qf;
#pragma unroll
        for (int j = 0; j < 2; j++) {
            f32x4 s = z;
            s = MFMA16(af[j][0], c0, s);
            s = MFMA16(af[j][1], c1, s);
            float pe0 = __expf(s[0]), pe1 = __expf(s[1]);
            float pe2 = __expf(s[2]), pe3 = __expf(s[3]);
            *reinterpret_cast<int*>(Eb + ((size_t)qt * 128 + kt0 + j) * 256) =
                pk_fp8x4(pe0, pe1, pe2, pe3);
            float v = pe0 + pe1 + pe2 + pe3;
            v += __shfl_xor(v, 16, 64);
            v += __shfl_xor(v, 32, 64);
            if (g == 0) (j ? Rp1 : Rp0)[qf * 16 + l15] = v;
        }
        c0 = n0_; c1 = n1_;
    }
}

// Rq[b][q] = 1 / sum_p Rpart[bl][p][q]
__global__ __launch_bounds__(256) void k_rsum(const float* __restrict__ Rpart, float* __restrict__ Rq, int b0) {
    int idx = blockIdx.x * 256 + threadIdx.x;
    int bl = idx >> 11, q = idx & 2047;
    const float* rp = Rpart + (size_t)bl * 128 * LQ + q;
    float s = 0.f;
    for (int p = 0; p < 128; p++) s += rp[(size_t)p * LQ];
    Rq[(size_t)(b0 + bl) * LQ + q] = 1.f / s;
}

// Cpart[bl][qc][k] = sum over 512 q (32 qt) of E0t[qt][kt]*Rq.  grid (32, 4, G)
__global__ __launch_bounds__(256) void k_colsum(const u8* __restrict__ E0t, const float* __restrict__ Rq,
                                                float* __restrict__ Cpart, int b0)
{
    const int qc = blockIdx.y, bl = blockIdx.z;
    const int tid = threadIdx.x, w = tid >> 6, lane = tid & 63, l15 = lane & 15, g = lane >> 4;
    const int kt = blockIdx.x * 4 + w;
    const u8* base = E0t + (size_t)bl * LQ * LK + (size_t)kt * 256 + l15 * 16 + g * 4;
    const float* rq = Rq + (size_t)(b0 + bl) * LQ;
    float acc[4] = {0.f, 0.f, 0.f, 0.f};
#pragma unroll 4
    for (int i = 0; i < 32; i++) {
        int qt = qc * 32 + i;
        unsigned int u = *reinterpret_cast<const unsigned int*>(base + (size_t)qt * 32768);
        float wgt = rq[qt * 16 + l15];
#pragma unroll
        for (int by = 0; by < 4; by++) {
            unsigned int f = 0x3C000000u + (((u >> (8 * by)) & 0x7Fu) << 20);
            acc[by] += __uint_as_float(f) * wgt;
        }
    }
#pragma unroll
    for (int by = 0; by < 4; by++) {
        acc[by] += __shfl_xor(acc[by], 1, 64);
        acc[by] += __shfl_xor(acc[by], 2, 64);
        acc[by] += __shfl_xor(acc[by], 4, 64);
        acc[by] += __shfl_xor(acc[by], 8, 64);
    }
    if (l15 == 0) {
        float4 v4 = make_float4(acc[0], acc[1], acc[2], acc[3]);
        *reinterpret_cast<float4*>(Cpart + ((size_t)bl * 4 + qc) * LK + kt * 16 + g * 4) = v4;
    }
}

// ci[b][k] = 1/(eps + sum_qc Cpart)
__global__ __launch_bounds__(256) void k_csum(const float* __restrict__ Cpart, float* __restrict__ ci, int b0) {
    int idx = blockIdx.x * 256 + threadIdx.x;
    int bl = idx >> 11, k = idx & 2047;
    const float* cp = Cpart + (size_t)bl * 4 * LK + k;
    float s = 0.f;
#pragma unroll
    for (int p = 0; p < 4; p++) s += cp[(size_t)p * LK];
    ci[(size_t)(b0 + bl) * LK + k] = 1.f / (EPSF + s);
}

// wvS[b][d][k] = fp8( (value[k,b,:] @ WVb[d,:]) * ci[b][k] )
// A (value f32, strided rows) gather-staged; B = WVb direct (L2-resident 512 KB).
// grid (LK/128, DD/128, G)
__global__ __launch_bounds__(256) void k_projv(const float* __restrict__ value, const u16* __restrict__ WVb,
                                               const float* __restrict__ ci, u8* __restrict__ wvS, int b0)
{
    const int b = b0 + blockIdx.z, k0 = blockIdx.x * 128, n0 = blockIdx.y * 128;
    const int tid = threadIdx.x, wv = tid >> 6, lane = tid & 63, l15 = lane & 15, g = lane >> 4;
    const int qg = wv >> 1, dg = wv & 1;

    __shared__ __align__(16) float As[2][128 * 32];   // 2 x 16 KB

    const int srow = wv * 8 + (lane >> 3);
    const int scb = ((lane & 7) * 16) ^ ((srow & 7) << 4);

    f32x4 z = {0.f, 0.f, 0.f, 0.f};
    f32x4 acc[4][4];
#pragma unroll
    for (int m = 0; m < 4; m++)
#pragma unroll
        for (int nf = 0; nf < 4; nf++) acc[m][nf] = z;

    auto stage = [&](int buf, int kt) {
#pragma unroll
        for (int p = 0; p < 4; ++p) {
            const char* src = (const char*)(value + ((size_t)(k0 + p * 32 + srow) * BB + b) * DD) + kt * 4 + scb;
            gload16(src, (char*)As[buf] + p * 4096 + wv * 1024);
        }
    };
    stage(0, 0);
    int buf = 0;
    for (int tt = 0; tt < 16; ++tt) {
        __syncthreads();
        if (tt + 1 < 16) stage(buf ^ 1, (tt + 1) * 32);
        bf16x8 af[4];
#pragma unroll
        for (int m = 0; m < 4; m++) {
            int row = qg * 64 + m * 16 + l15;
            const char* rp = (const char*)As[buf] + row * 128;
            int xs = (row & 7) << 4;
            float4 fa = *reinterpret_cast<const float4*>(rp + ((g * 32) ^ xs));
            float4 fb = *reinterpret_cast<const float4*>(rp + ((g * 32 + 16) ^ xs));
            af[m] = cvt8(fa, fb);
        }
#pragma unroll
        for (int nf = 0; nf < 4; nf++) {
            bf16x8 bw = *reinterpret_cast<const bf16x8*>(WVb + (size_t)(n0 + dg * 64 + nf * 16 + l15) * DD + tt * 32 + g * 8);
#pragma unroll
            for (int m = 0; m < 4; m++) acc[m][nf] = MFMA16(af[m], bw, acc[m][nf]);
        }
        buf ^= 1;
    }
#pragma unroll
    for (int m = 0; m < 4; m++) {
        float cv[4];
        int kb = k0 + qg * 64 + m * 16 + g * 4;
#pragma unroll
        for (int j = 0; j < 4; j++) cv[j] = ci[(size_t)b * LK + kb + j];
#pragma unroll
        for (int nf = 0; nf < 4; nf++) {
            int d = n0 + dg * 64 + nf * 16 + l15;
            *reinterpret_cast<int*>(wvS + ((size_t)b * DD + d) * LK + kb) =
                pk_fp8x4(acc[m][nf][0] * cv[0], acc[m][nf][1] * cv[1],
                         acc[m][nf][2] * cv[2], acc[m][nf][3] * cv[3]);
        }
    }
}

// t[q,b,:] = query - Rq[q] * (E0t @ wvS^T).  fp8 GEMM, BK=128.
__global__ __launch_bounds__(256, 3) void k_pvgemm(const float* __restrict__ query,
                                                   const u8* __restrict__ E0t,
                                                   const u8* __restrict__ wvS,
                                                   const float* __restrict__ Rq,
                                                   u16* __restrict__ tout, int b0, int G)
{
    const int i = blockIdx.x;
    int bl, tile;
    if (G == 16) { bl = (i & 7) + 8 * (i >> 9); tile = (i >> 3) & 63; }
    else         { bl = i % G; tile = i / G; }
    const int b = b0 + bl;
    const int q0 = (tile >> 2) * 128, n0 = (tile & 3) * 128;
    const int tid = threadIdx.x, wv = tid >> 6, lane = tid & 63, l15 = lane & 15, g = lane >> 4;
    const int qg = wv >> 1, dg = wv & 1;

    __shared__ __align__(16) char As[16384], Bs[16384];

    const u8* Eb = E0t + (size_t)bl * LQ * LK;
    const u8* Vb = wvS + (size_t)b * DD * LK;

    const char* gAt = (const char*)Eb + (size_t)(q0 >> 4) * 128 * 256;
    const int srow = wv * 8 + (lane >> 3);
    const int scb = ((lane & 7) * 16) ^ ((srow & 7) << 4);
    const char* gB = (const char*)Vb + (size_t)(n0 + srow) * LK + scb;
    const size_t rstepB = (size_t)32 * LK;

    f32x4 z = {0.f, 0.f, 0.f, 0.f};
    f32x4 acc[4][4];
#pragma unroll
    for (int m = 0; m < 4; m++)
#pragma unroll
        for (int nf = 0; nf < 4; nf++) acc[m][nf] = z;

    auto stage = [&](int t) {
#pragma unroll
        for (int p = 0; p < 4; ++p) {
            int c = wv * 4 + p;
            gload16(gAt + ((size_t)(c >> 1) * 128 + t * 8) * 256 + (c & 1) * 1024 + lane * 16,
                    (char*)As + c * 1024);
            gload16(gB + p * rstepB + t * 128, (char*)Bs + p * 4096 + wv * 1024);
        }
    };
    stage(0);

    for (int t = 0; t < LK / 128; ++t) {
        __syncthreads();
        i64 af[4][4], bv[4][4];
#pragma unroll
        for (int m = 0; m < 4; m++) {
            const char* rp = (const char*)As + (qg * 4 + m) * 2048 + l15 * 16 + (g & 1) * 8;
#pragma unroll
            for (int kk = 0; kk < 4; kk++)
                af[m][kk] = *reinterpret_cast<const i64*>(rp + (kk * 2 + (g >> 1)) * 256);
        }
#pragma unroll
        for (int nf = 0; nf < 4; nf++) {
            int row = dg * 64 + nf * 16 + l15;
            const char* rp = (const char*)Bs + row * 128;
            int x = (row & 7) << 4;
#pragma unroll
            for (int kk = 0; kk < 4; kk++)
                bv[nf][kk] = *reinterpret_cast<const i64*>(rp + ((kk * 32 + g * 8) ^ x));
        }
        __syncthreads();
        if (t + 1 < LK / 128) stage(t + 1);
#pragma unroll
        for (int kk = 0; kk < 4; kk++)
#pragma unroll
            for (int nf = 0; nf < 4; nf++)
#pragma unroll
                for (int m = 0; m < 4; m++)
                    acc[m][nf] = MFMAF8(af[m][kk], bv[nf][kk], acc[m][nf]);
    }
#pragma unroll
    for (int m = 0; m < 4; m++) {
        float rqv[4];
#pragma unroll
        for (int j = 0; j < 4; j++)
            rqv[j] = Rq[(size_t)b * LQ + q0 + qg * 64 + m * 16 + g * 4 + j];
#pragma unroll
        for (int nf = 0; nf < 4; nf++)
#pragma unroll
            for (int j = 0; j < 4; j++) {
                int q = q0 + qg * 64 + m * 16 + g * 4 + j;
                int d = n0 + dg * 64 + nf * 16 + l15;
                size_t idx = ((size_t)q * BB + b) * DD + d;
                tout[idx] = f2bf(query[idx] - acc[m][nf][j] * rqv[j]);
            }
    }
}

// out = relu( t @ Wtb^T ): 128x128 tile, bf16 staged, K=512
__global__ __launch_bounds__(256, 3) void k_final(const u16* __restrict__ t, const u16* __restrict__ Wtb,
                                                  float* __restrict__ out)
{
    const int r0 = blockIdx.x * 128, n0 = blockIdx.y * 128;
    const int tid = threadIdx.x, wv = tid >> 6, lane = tid & 63, l15 = lane & 15, g = lane >> 4;
    const int qg = wv >> 1, dg = wv & 1;

    __shared__ __align__(16) u16 As[128 * 64], Bs[128 * 64];

    const int srow = wv * 8 + (lane >> 3);
    const int scb = ((lane & 7) * 16) ^ ((srow & 7) << 4);
    const char* gA = (const char*)(t + (size_t)(r0 + srow) * DD) + scb;
    const char* gB = (const char*)(Wtb + (size_t)(n0 + srow) * DD) + scb;
    const size_t rstep = (size_t)32 * DD * 2;

    f32x4 z = {0.f, 0.f, 0.f, 0.f};
    f32x4 acc[4][4];
#pragma unroll
    for (int m = 0; m < 4; m++)
#pragma unroll
        for (int nf = 0; nf < 4; nf++) acc[m][nf] = z;

#pragma unroll
    for (int p = 0; p < 4; ++p) {
        gload16(gA + p * rstep, (char*)As + p * 4096 + wv * 1024);
        gload16(gB + p * rstep, (char*)Bs + p * 4096 + wv * 1024);
    }

    for (int tt = 0; tt < DD / 64; ++tt) {
        __syncthreads();
        bf16x8 af[4][2], bv[4][2];
#pragma unroll
        for (int m = 0; m < 4; m++) {
            int row = qg * 64 + m * 16 + l15;
            const char* rp = (const char*)As + row * 128;
            int x = (row & 7) << 4;
#pragma unroll
            for (int kk = 0; kk < 2; kk++)
                af[m][kk] = *reinterpret_cast<const bf16x8*>(rp + ((kk * 64 + g * 16) ^ x));
        }
#pragma unroll
        for (int nf = 0; nf < 4; nf++) {
            int row = dg * 64 + nf * 16 + l15;
            const char* rp = (const char*)Bs + row * 128;
            int x = (row & 7) << 4;
#pragma unroll
            for (int kk = 0; kk < 2; kk++)
                bv[nf][kk] = *reinterpret_cast<const bf16x8*>(rp + ((kk * 64 + g * 16) ^ x));
        }
        __syncthreads();
        if (tt + 1 < DD / 64) {
            int ktb = (tt + 1) * 128;
#pragma unroll
            for (int p = 0; p < 4; ++p) {
                gload16(gA + p * rstep + ktb, (char*)As + p * 4096 + wv * 1024);
                gload16(gB + p * rstep + ktb, (char*)Bs + p * 4096 + wv * 1024);
            }
        }
#pragma unroll
        for (int nf = 0; nf < 4; nf++)
#pragma unroll
            for (int m = 0; m < 4; m++) {
                acc[m][nf] = MFMA16(af[m][0], bv[nf][0], acc[m][nf]);
                acc[m][nf] = MFMA16(af[m][1], bv[nf][1], acc[m][nf]);
            }
    }
#pragma unroll
    for (int m = 0; m < 4; m++)
#pragma unroll
        for (int nf = 0; nf < 4; nf++)
#pragma unroll
            for (int j = 0; j < 4; j++)
                out[(size_t)(r0 + qg * 64 + m * 16 + g * 4 + j) * DD + n0 + dg * 64 + nf * 16 + l15] =
                    fmaxf(acc[m][nf][j], 0.f);
}

extern "C" void kernel_launch(void* const* d_in, const int* in_sizes, int n_in,
                              void* d_out, int out_size, void* d_ws, size_t ws_size,
                              hipStream_t stream)
{
    const float* query = (const float*)d_in[0];
    const float* key   = (const float*)d_in[1];
    const float* value = (const float*)d_in[2];
    const float* WK    = (const float*)d_in[3];
    const float* WQ    = (const float*)d_in[4];
    const float* WV    = (const float*)d_in[5];
    const float* Wt    = (const float*)d_in[6];
    float* out = (float*)d_out;

    char* ws = (char*)d_ws;
    u16*   wqb = (u16*)(ws);                                   //  4 MB [B][LQ][64] bf16
    u16*   wkb = (u16*)(ws + (4u << 20));                      //  4 MB [B][LK][64] bf16
    u8*    wvS = (u8*)(ws + (8u << 20));                       // 16 MB [B][512][LK] fp8
    u16*   t   = (u16*)(ws + (24u << 20));                     // 32 MB [LQ][B][512] bf16
    float* Rq  = (float*)(ws + (88u << 20));                   // 128 KB [B][LQ] f32
    float* ci  = (float*)(ws + (88u << 20) + (128u << 10));    // 128 KB [B][LK] f32
    u16*   WQb = (u16*)(ws + (88u << 20) + (256u << 10));      // 64 KB
    u16*   WKb = (u16*)(ws + (88u << 20) + (320u << 10));      // 64 KB
    u16*   WVb = (u16*)(ws + (88u << 20) + (384u << 10));      // 512 KB
    u16*   Wtb = (u16*)(ws + (88u << 20) + (896u << 10));      // 512 KB

    // per-group buffers: E0t (4MB/b) + Rpart (1MB/b) + Cpart (32KB/b)
    const size_t fixed = 90ull << 20;
    const size_t perG = (4ull << 20) + (1ull << 20) + (32ull << 10);
    int G = 0;
    for (int g = 16; g >= 1; g >>= 1)
        if (fixed + (size_t)g * perG <= ws_size) { G = g; break; }
    if (G == 0) G = 1;
    u8*    E0    = (u8*)(ws + fixed);
    float* Rpart = (float*)(ws + fixed + ((size_t)G << 22));
    float* Cpart = (float*)(ws + fixed + ((size_t)G << 22) + ((size_t)G << 20));

    k_cvt<<<32, 256, 0, stream>>>(WQ, WQb, DKK * DD);
    k_cvt<<<32, 256, 0, stream>>>(WK, WKb, DKK * DD);
    k_cvt<<<256, 256, 0, stream>>>(WV, WVb, DD * DD);
    k_cvt<<<256, 256, 0, stream>>>(Wt, Wtb, DD * DD);

    k_projqk<<<dim3(LQ / 128, BB, 2), 256, 0, stream>>>(query, key, WQb, WKb, wqb, wkb);

    for (int b0 = 0; b0 < BB; b0 += G) {
        k_score<<<dim3(LK / 128, LQ / 512, G), 256, 0, stream>>>(wqb, wkb, E0, Rpart, b0);
        k_rsum<<<G * 8, 256, 0, stream>>>(Rpart, Rq, b0);
        k_colsum<<<dim3(32, 4, G), 256, 0, stream>>>(E0, Rq, Cpart, b0);
        k_csum<<<G * 8, 256, 0, stream>>>(Cpart, ci, b0);
        k_projv<<<dim3(LK / 128, DD / 128, G), 256, 0, stream>>>(value, WVb, ci, wvS, b0);
        k_pvgemm<<<64 * G, 256, 0, stream>>>(query, E0, wvS, Rq, t, b0, G);
    }

    k_final<<<dim3(LQ * BB / 128, DD / 128), 256, 0, stream>>>(t, Wtb, out);
}

// Round 15
// 257.271 us; speedup vs baseline: 1.1803x; 1.0026x over previous
//
#include <hip/hip_runtime.h>

#define LQ 2048
#define LK 2048
#define BB 16
#define DD 512
#define DKK 64
#define EPSF 1e-9f

typedef unsigned short u16;
typedef unsigned char u8;
typedef long i64;
typedef __attribute__((ext_vector_type(8))) short bf16x8;
typedef __attribute__((ext_vector_type(4))) float f32x4;
#define MFMA16(a, b, c) __builtin_amdgcn_mfma_f32_16x16x32_bf16(a, b, c, 0, 0, 0)
#define MFMAF8(a, b, c) __builtin_amdgcn_mfma_f32_16x16x32_fp8_fp8(a, b, c, 0, 0, 0)

__device__ inline u16 f2bf(float f) {
    unsigned int u = __float_as_uint(f);
    u += 0x7fffu + ((u >> 16) & 1u);   // RNE
    return (u16)(u >> 16);
}
// hardware packed f32->bf16 (RNE), 2 elements/instruction: 4 VALU ops per 8 elements
__device__ inline bf16x8 cvt8(float4 a, float4 b) {
    union { bf16x8 v; unsigned int u[4]; } r;
    asm("v_cvt_pk_bf16_f32 %0, %1, %2" : "=v"(r.u[0]) : "v"(a.x), "v"(a.y));
    asm("v_cvt_pk_bf16_f32 %0, %1, %2" : "=v"(r.u[1]) : "v"(a.z), "v"(a.w));
    asm("v_cvt_pk_bf16_f32 %0, %1, %2" : "=v"(r.u[2]) : "v"(b.x), "v"(b.y));
    asm("v_cvt_pk_bf16_f32 %0, %1, %2" : "=v"(r.u[3]) : "v"(b.z), "v"(b.w));
    return r.v;
}
__device__ inline int pk_fp8x4(float a, float b, float c, float d) {
    int r = __builtin_amdgcn_cvt_pk_fp8_f32(a, b, 0, false);
    r = __builtin_amdgcn_cvt_pk_fp8_f32(c, d, r, true);
    return r;
}
__device__ inline void gload16(const void* g, void* l) {
    __builtin_amdgcn_global_load_lds((const __attribute__((address_space(1))) unsigned int*)g,
                                     (__attribute__((address_space(3))) unsigned int*)l, 16, 0, 0);
}

__global__ __launch_bounds__(256) void k_cvt(const float* __restrict__ src, u16* __restrict__ dst, int n) {
    int i = (blockIdx.x * 256 + threadIdx.x) * 4;
    if (i < n) {
        float4 v = *reinterpret_cast<const float4*>(src + i);
        *reinterpret_cast<ushort4*>(dst + i) = make_ushort4(f2bf(v.x), f2bf(v.y), f2bf(v.z), f2bf(v.w));
    }
}

// fused q/k projection + l2norm.  Staged-async A + XOR swizzle; hw-cvt on read; B direct (L2).
__global__ __launch_bounds__(256) void k_projqk(const float* __restrict__ xq, const float* __restrict__ xk,
                                                const u16* __restrict__ Wq, const u16* __restrict__ Wk,
                                                u16* __restrict__ yq, u16* __restrict__ yk)
{
    const float* x = blockIdx.z ? xk : xq;
    const u16* Wb = blockIdx.z ? Wk : Wq;
    u16* y = blockIdx.z ? yk : yq;
    const int b = blockIdx.y, r0 = blockIdx.x * 128;
    const int tid = threadIdx.x, wv = tid >> 6, lane = tid & 63, l15 = lane & 15, g = lane >> 4;

    __shared__ __align__(16) float As[2][128 * 32];   // 2 x 16 KB

    const int srow = wv * 8 + (lane >> 3);
    const int scb = ((lane & 7) * 16) ^ ((srow & 7) << 4);

    f32x4 z = {0.f, 0.f, 0.f, 0.f};
    f32x4 acc[2][4];
#pragma unroll
    for (int m = 0; m < 2; m++)
#pragma unroll
        for (int nf = 0; nf < 4; nf++) acc[m][nf] = z;

    auto stage = [&](int buf, int kt) {
#pragma unroll
        for (int p = 0; p < 4; ++p) {
            const char* src = (const char*)(x + ((size_t)(r0 + p * 32 + srow) * BB + b) * DD) + kt * 4 + scb;
            gload16(src, (char*)As[buf] + p * 4096 + wv * 1024);
        }
    };
    stage(0, 0);
    int buf = 0;
    for (int tt = 0; tt < 16; ++tt) {
        __syncthreads();
        if (tt + 1 < 16) stage(buf ^ 1, (tt + 1) * 32);
        bf16x8 af[2];
#pragma unroll
        for (int m = 0; m < 2; m++) {
            int row = wv * 32 + m * 16 + l15;
            const char* rp = (const char*)As[buf] + row * 128;
            int xs = (row & 7) << 4;
            float4 fa = *reinterpret_cast<const float4*>(rp + ((g * 32) ^ xs));
            float4 fb = *reinterpret_cast<const float4*>(rp + ((g * 32 + 16) ^ xs));
            af[m] = cvt8(fa, fb);
        }
#pragma unroll
        for (int nf = 0; nf < 4; nf++) {
            bf16x8 bw = *reinterpret_cast<const bf16x8*>(Wb + (size_t)(nf * 16 + l15) * DD + tt * 32 + g * 8);
            acc[0][nf] = MFMA16(af[0], bw, acc[0][nf]);
            acc[1][nf] = MFMA16(af[1], bw, acc[1][nf]);
        }
        buf ^= 1;
    }
#pragma unroll
    for (int m = 0; m < 2; m++) {
        float rn[4];
#pragma unroll
        for (int j = 0; j < 4; j++) {
            float t2 = acc[m][0][j] * acc[m][0][j] + acc[m][1][j] * acc[m][1][j]
                     + acc[m][2][j] * acc[m][2][j] + acc[m][3][j] * acc[m][3][j];
            t2 += __shfl_xor(t2, 1, 64);
            t2 += __shfl_xor(t2, 2, 64);
            t2 += __shfl_xor(t2, 4, 64);
            t2 += __shfl_xor(t2, 8, 64);
            rn[j] = 1.f / fmaxf(sqrtf(t2), 1e-12f);
        }
#pragma unroll
        for (int nf = 0; nf < 4; nf++)
#pragma unroll
            for (int j = 0; j < 4; j++) {
                int q = r0 + wv * 32 + m * 16 + g * 4 + j;
                y[((size_t)b * LQ + q) * DKK + nf * 16 + l15] = f2bf(acc[m][nf][j] * rn[j]);
            }
    }
}

// Single QK^T pass, TILED E0 output. Each wave owns TWO k-tiles (2x MFMA ILP per Q-frag).
__global__ __launch_bounds__(256) void k_score(const u16* __restrict__ wqb, const u16* __restrict__ wkb,
                                               u8* __restrict__ E0t, float* __restrict__ Rpart, int b0)
{
    const int bx = blockIdx.x, qc = blockIdx.y, bl = blockIdx.z, b = b0 + bl;
    const int tid = threadIdx.x, w = tid >> 6, lane = tid & 63, l15 = lane & 15, g = lane >> 4;
    const int kt0 = bx * 8 + w * 2;
    f32x4 z = {0.f, 0.f, 0.f, 0.f};

    bf16x8 af[2][2];
#pragma unroll
    for (int j = 0; j < 2; j++) {
        const u16* ar = wkb + ((size_t)b * LK + (kt0 + j) * 16 + l15) * DKK;
        af[j][0] = *reinterpret_cast<const bf16x8*>(ar + g * 8);
        af[j][1] = *reinterpret_cast<const bf16x8*>(ar + 32 + g * 8);
    }
    u8* Eb = E0t + (size_t)bl * LQ * LK + l15 * 16 + g * 4;
    float* Rp0 = Rpart + ((size_t)bl * 128 + kt0) * LQ + qc * 512;
    float* Rp1 = Rp0 + LQ;
    const u16* qbase = wqb + ((size_t)b * LQ + qc * 512 + l15) * DKK + g * 8;

    bf16x8 c0 = *reinterpret_cast<const bf16x8*>(qbase);
    bf16x8 c1 = *reinterpret_cast<const bf16x8*>(qbase + 32);
    bf16x8 n0_ = c0, n1_ = c1;

#pragma unroll 4
    for (int qf = 0; qf < 32; qf++) {
        if (qf < 31) {
            const u16* br = qbase + (size_t)(qf + 1) * 16 * DKK;
            n0_ = *reinterpret_cast<const bf16x8*>(br);
            n1_ = *reinterpret_cast<const bf16x8*>(br + 32);
        }
        __builtin_amdgcn_sched_barrier(0);
        int qt = qc * 32 + qf;
#pragma unroll
        for (int j = 0; j < 2; j++) {
            f32x4 s = z;
            s = MFMA16(af[j][0], c0, s);
            s = MFMA16(af[j][1], c1, s);
            float pe0 = __expf(s[0]), pe1 = __expf(s[1]);
            float pe2 = __expf(s[2]), pe3 = __expf(s[3]);
            *reinterpret_cast<int*>(Eb + ((size_t)qt * 128 + kt0 + j) * 256) =
                pk_fp8x4(pe0, pe1, pe2, pe3);
            float v = pe0 + pe1 + pe2 + pe3;
            v += __shfl_xor(v, 16, 64);
            v += __shfl_xor(v, 32, 64);
            if (g == 0) (j ? Rp1 : Rp0)[qf * 16 + l15] = v;
        }
        c0 = n0_; c1 = n1_;
    }
}

// Rq[b][q] = 1 / sum_p Rpart[bl][p][q]
__global__ __launch_bounds__(256) void k_rsum(const float* __restrict__ Rpart, float* __restrict__ Rq, int b0) {
    int idx = blockIdx.x * 256 + threadIdx.x;
    int bl = idx >> 11, q = idx & 2047;
    const float* rp = Rpart + (size_t)bl * 128 * LQ + q;
    float s = 0.f;
    for (int p = 0; p < 128; p++) s += rp[(size_t)p * LQ];
    Rq[(size_t)(b0 + bl) * LQ + q] = 1.f / s;
}

// Cpart[bl][qc][k] = sum over 512 q (32 qt) of E0t[qt][kt]*Rq.  grid (32, 4, G)
__global__ __launch_bounds__(256) void k_colsum(const u8* __restrict__ E0t, const float* __restrict__ Rq,
                                                float* __restrict__ Cpart, int b0)
{
    const int qc = blockIdx.y, bl = blockIdx.z;
    const int tid = threadIdx.x, w = tid >> 6, lane = tid & 63, l15 = lane & 15, g = lane >> 4;
    const int kt = blockIdx.x * 4 + w;
    const u8* base = E0t + (size_t)bl * LQ * LK + (size_t)kt * 256 + l15 * 16 + g * 4;
    const float* rq = Rq + (size_t)(b0 + bl) * LQ;
    float acc[4] = {0.f, 0.f, 0.f, 0.f};
#pragma unroll 4
    for (int i = 0; i < 32; i++) {
        int qt = qc * 32 + i;
        unsigned int u = *reinterpret_cast<const unsigned int*>(base + (size_t)qt * 32768);
        float wgt = rq[qt * 16 + l15];
#pragma unroll
        for (int by = 0; by < 4; by++) {
            unsigned int f = 0x3C000000u + (((u >> (8 * by)) & 0x7Fu) << 20);
            acc[by] += __uint_as_float(f) * wgt;
        }
    }
#pragma unroll
    for (int by = 0; by < 4; by++) {
        acc[by] += __shfl_xor(acc[by], 1, 64);
        acc[by] += __shfl_xor(acc[by], 2, 64);
        acc[by] += __shfl_xor(acc[by], 4, 64);
        acc[by] += __shfl_xor(acc[by], 8, 64);
    }
    if (l15 == 0) {
        float4 v4 = make_float4(acc[0], acc[1], acc[2], acc[3]);
        *reinterpret_cast<float4*>(Cpart + ((size_t)bl * 4 + qc) * LK + kt * 16 + g * 4) = v4;
    }
}

// ci[b][k] = 1/(eps + sum_qc Cpart)
__global__ __launch_bounds__(256) void k_csum(const float* __restrict__ Cpart, float* __restrict__ ci, int b0) {
    int idx = blockIdx.x * 256 + threadIdx.x;
    int bl = idx >> 11, k = idx & 2047;
    const float* cp = Cpart + (size_t)bl * 4 * LK + k;
    float s = 0.f;
#pragma unroll
    for (int p = 0; p < 4; p++) s += cp[(size_t)p * LK];
    ci[(size_t)(b0 + bl) * LK + k] = 1.f / (EPSF + s);
}

// wvS[b][d][k] = fp8( (value[k,b,:] @ WVb[d,:]) * ci[b][k] )
__global__ __launch_bounds__(256) void k_projv(const float* __restrict__ value, const u16* __restrict__ WVb,
                                               const float* __restrict__ ci, u8* __restrict__ wvS, int b0)
{
    const int b = b0 + blockIdx.z, k0 = blockIdx.x * 128, n0 = blockIdx.y * 128;
    const int tid = threadIdx.x, wv = tid >> 6, lane = tid & 63, l15 = lane & 15, g = lane >> 4;
    const int qg = wv >> 1, dg = wv & 1;

    __shared__ __align__(16) float As[2][128 * 32];   // 2 x 16 KB

    const int srow = wv * 8 + (lane >> 3);
    const int scb = ((lane & 7) * 16) ^ ((srow & 7) << 4);

    f32x4 z = {0.f, 0.f, 0.f, 0.f};
    f32x4 acc[4][4];
#pragma unroll
    for (int m = 0; m < 4; m++)
#pragma unroll
        for (int nf = 0; nf < 4; nf++) acc[m][nf] = z;

    auto stage = [&](int buf, int kt) {
#pragma unroll
        for (int p = 0; p < 4; ++p) {
            const char* src = (const char*)(value + ((size_t)(k0 + p * 32 + srow) * BB + b) * DD) + kt * 4 + scb;
            gload16(src, (char*)As[buf] + p * 4096 + wv * 1024);
        }
    };
    stage(0, 0);
    int buf = 0;
    for (int tt = 0; tt < 16; ++tt) {
        __syncthreads();
        if (tt + 1 < 16) stage(buf ^ 1, (tt + 1) * 32);
        bf16x8 af[4];
#pragma unroll
        for (int m = 0; m < 4; m++) {
            int row = qg * 64 + m * 16 + l15;
            const char* rp = (const char*)As[buf] + row * 128;
            int xs = (row & 7) << 4;
            float4 fa = *reinterpret_cast<const float4*>(rp + ((g * 32) ^ xs));
            float4 fb = *reinterpret_cast<const float4*>(rp + ((g * 32 + 16) ^ xs));
            af[m] = cvt8(fa, fb);
        }
#pragma unroll
        for (int nf = 0; nf < 4; nf++) {
            bf16x8 bw = *reinterpret_cast<const bf16x8*>(WVb + (size_t)(n0 + dg * 64 + nf * 16 + l15) * DD + tt * 32 + g * 8);
#pragma unroll
            for (int m = 0; m < 4; m++) acc[m][nf] = MFMA16(af[m], bw, acc[m][nf]);
        }
        buf ^= 1;
    }
#pragma unroll
    for (int m = 0; m < 4; m++) {
        float cv[4];
        int kb = k0 + qg * 64 + m * 16 + g * 4;
#pragma unroll
        for (int j = 0; j < 4; j++) cv[j] = ci[(size_t)b * LK + kb + j];
#pragma unroll
        for (int nf = 0; nf < 4; nf++) {
            int d = n0 + dg * 64 + nf * 16 + l15;
            *reinterpret_cast<int*>(wvS + ((size_t)b * DD + d) * LK + kb) =
                pk_fp8x4(acc[m][nf][0] * cv[0], acc[m][nf][1] * cv[1],
                         acc[m][nf][2] * cv[2], acc[m][nf][3] * cv[3]);
        }
    }
}

// t[q,b,:] = query - Rq[q] * (E0t @ wvS^T).  fp8 GEMM, BK=128.
__global__ __launch_bounds__(256, 3) void k_pvgemm(const float* __restrict__ query,
                                                   const u8* __restrict__ E0t,
                                                   const u8* __restrict__ wvS,
                                                   const float* __restrict__ Rq,
                                                   u16* __restrict__ tout, int b0, int G)
{
    const int i = blockIdx.x;
    int bl, tile;
    if (G == 16) { bl = (i & 7) + 8 * (i >> 9); tile = (i >> 3) & 63; }
    else         { bl = i % G; tile = i / G; }
    const int b = b0 + bl;
    const int q0 = (tile >> 2) * 128, n0 = (tile & 3) * 128;
    const int tid = threadIdx.x, wv = tid >> 6, lane = tid & 63, l15 = lane & 15, g = lane >> 4;
    const int qg = wv >> 1, dg = wv & 1;

    __shared__ __align__(16) char As[16384], Bs[16384];

    const u8* Eb = E0t + (size_t)bl * LQ * LK;
    const u8* Vb = wvS + (size_t)b * DD * LK;

    const char* gAt = (const char*)Eb + (size_t)(q0 >> 4) * 128 * 256;
    const int srow = wv * 8 + (lane >> 3);
    const int scb = ((lane & 7) * 16) ^ ((srow & 7) << 4);
    const char* gB = (const char*)Vb + (size_t)(n0 + srow) * LK + scb;
    const size_t rstepB = (size_t)32 * LK;

    f32x4 z = {0.f, 0.f, 0.f, 0.f};
    f32x4 acc[4][4];
#pragma unroll
    for (int m = 0; m < 4; m++)
#pragma unroll
        for (int nf = 0; nf < 4; nf++) acc[m][nf] = z;

    auto stage = [&](int t) {
#pragma unroll
        for (int p = 0; p < 4; ++p) {
            int c = wv * 4 + p;
            gload16(gAt + ((size_t)(c >> 1) * 128 + t * 8) * 256 + (c & 1) * 1024 + lane * 16,
                    (char*)As + c * 1024);
            gload16(gB + p * rstepB + t * 128, (char*)Bs + p * 4096 + wv * 1024);
        }
    };
    stage(0);

    for (int t = 0; t < LK / 128; ++t) {
        __syncthreads();
        i64 af[4][4], bv[4][4];
#pragma unroll
        for (int m = 0; m < 4; m++) {
            const char* rp = (const char*)As + (qg * 4 + m) * 2048 + l15 * 16 + (g & 1) * 8;
#pragma unroll
            for (int kk = 0; kk < 4; kk++)
                af[m][kk] = *reinterpret_cast<const i64*>(rp + (kk * 2 + (g >> 1)) * 256);
        }
#pragma unroll
        for (int nf = 0; nf < 4; nf++) {
            int row = dg * 64 + nf * 16 + l15;
            const char* rp = (const char*)Bs + row * 128;
            int x = (row & 7) << 4;
#pragma unroll
            for (int kk = 0; kk < 4; kk++)
                bv[nf][kk] = *reinterpret_cast<const i64*>(rp + ((kk * 32 + g * 8) ^ x));
        }
        __syncthreads();
        if (t + 1 < LK / 128) stage(t + 1);
#pragma unroll
        for (int kk = 0; kk < 4; kk++)
#pragma unroll
            for (int nf = 0; nf < 4; nf++)
#pragma unroll
                for (int m = 0; m < 4; m++)
                    acc[m][nf] = MFMAF8(af[m][kk], bv[nf][kk], acc[m][nf]);
    }
#pragma unroll
    for (int m = 0; m < 4; m++) {
        float rqv[4];
#pragma unroll
        for (int j = 0; j < 4; j++)
            rqv[j] = Rq[(size_t)b * LQ + q0 + qg * 64 + m * 16 + g * 4 + j];
#pragma unroll
        for (int nf = 0; nf < 4; nf++)
#pragma unroll
            for (int j = 0; j < 4; j++) {
                int q = q0 + qg * 64 + m * 16 + g * 4 + j;
                int d = n0 + dg * 64 + nf * 16 + l15;
                size_t idx = ((size_t)q * BB + b) * DD + d;
                tout[idx] = f2bf(query[idx] - acc[m][nf][j] * rqv[j]);
            }
    }
}

// out = relu( t @ Wtb^T ): 128x128 tile, bf16 staged, K=512
__global__ __launch_bounds__(256, 3) void k_final(const u16* __restrict__ t, const u16* __restrict__ Wtb,
                                                  float* __restrict__ out)
{
    const int r0 = blockIdx.x * 128, n0 = blockIdx.y * 128;
    const int tid = threadIdx.x, wv = tid >> 6, lane = tid & 63, l15 = lane & 15, g = lane >> 4;
    const int qg = wv >> 1, dg = wv & 1;

    __shared__ __align__(16) u16 As[128 * 64], Bs[128 * 64];

    const int srow = wv * 8 + (lane >> 3);
    const int scb = ((lane & 7) * 16) ^ ((srow & 7) << 4);
    const char* gA = (const char*)(t + (size_t)(r0 + srow) * DD) + scb;
    const char* gB = (const char*)(Wtb + (size_t)(n0 + srow) * DD) + scb;
    const size_t rstep = (size_t)32 * DD * 2;

    f32x4 z = {0.f, 0.f, 0.f, 0.f};
    f32x4 acc[4][4];
#pragma unroll
    for (int m = 0; m < 4; m++)
#pragma unroll
        for (int nf = 0; nf < 4; nf++) acc[m][nf] = z;

#pragma unroll
    for (int p = 0; p < 4; ++p) {
        gload16(gA + p * rstep, (char*)As + p * 4096 + wv * 1024);
        gload16(gB + p * rstep, (char*)Bs + p * 4096 + wv * 1024);
    }

    for (int tt = 0; tt < DD / 64; ++tt) {
        __syncthreads();
        bf16x8 af[4][2], bv[4][2];
#pragma unroll
        for (int m = 0; m < 4; m++) {
            int row = qg * 64 + m * 16 + l15;
            const char* rp = (const char*)As + row * 128;
            int x = (row & 7) << 4;
#pragma unroll
            for (int kk = 0; kk < 2; kk++)
                af[m][kk] = *reinterpret_cast<const bf16x8*>(rp + ((kk * 64 + g * 16) ^ x));
        }
#pragma unroll
        for (int nf = 0; nf < 4; nf++) {
            int row = dg * 64 + nf * 16 + l15;
            const char* rp = (const char*)Bs + row * 128;
            int x = (row & 7) << 4;
#pragma unroll
            for (int kk = 0; kk < 2; kk++)
                bv[nf][kk] = *reinterpret_cast<const bf16x8*>(rp + ((kk * 64 + g * 16) ^ x));
        }
        __syncthreads();
        if (tt + 1 < DD / 64) {
            int ktb = (tt + 1) * 128;
#pragma unroll
            for (int p = 0; p < 4; ++p) {
                gload16(gA + p * rstep + ktb, (char*)As + p * 4096 + wv * 1024);
                gload16(gB + p * rstep + ktb, (char*)Bs + p * 4096 + wv * 1024);
            }
        }
#pragma unroll
        for (int nf = 0; nf < 4; nf++)
#pragma unroll
            for (int m = 0; m < 4; m++) {
                acc[m][nf] = MFMA16(af[m][0], bv[nf][0], acc[m][nf]);
                acc[m][nf] = MFMA16(af[m][1], bv[nf][1], acc[m][nf]);
            }
    }
#pragma unroll
    for (int m = 0; m < 4; m++)
#pragma unroll
        for (int nf = 0; nf < 4; nf++)
#pragma unroll
            for (int j = 0; j < 4; j++)
                out[(size_t)(r0 + qg * 64 + m * 16 + g * 4 + j) * DD + n0 + dg * 64 + nf * 16 + l15] =
                    fmaxf(acc[m][nf][j], 0.f);
}

extern "C" void kernel_launch(void* const* d_in, const int* in_sizes, int n_in,
                              void* d_out, int out_size, void* d_ws, size_t ws_size,
                              hipStream_t stream)
{
    const float* query = (const float*)d_in[0];
    const float* key   = (const float*)d_in[1];
    const float* value = (const float*)d_in[2];
    const float* WK    = (const float*)d_in[3];
    const float* WQ    = (const float*)d_in[4];
    const float* WV    = (const float*)d_in[5];
    const float* Wt    = (const float*)d_in[6];
    float* out = (float*)d_out;

    char* ws = (char*)d_ws;
    u16*   wqb = (u16*)(ws);                                   //  4 MB [B][LQ][64] bf16
    u16*   wkb = (u16*)(ws + (4u << 20));                      //  4 MB [B][LK][64] bf16
    u8*    wvS = (u8*)(ws + (8u << 20));                       // 16 MB [B][512][LK] fp8
    u16*   t   = (u16*)(ws + (24u << 20));                     // 32 MB [LQ][B][512] bf16
    float* Rq  = (float*)(ws + (88u << 20));                   // 128 KB [B][LQ] f32
    float* ci  = (float*)(ws + (88u << 20) + (128u << 10));    // 128 KB [B][LK] f32
    u16*   WQb = (u16*)(ws + (88u << 20) + (256u << 10));      // 64 KB
    u16*   WKb = (u16*)(ws + (88u << 20) + (320u << 10));      // 64 KB
    u16*   WVb = (u16*)(ws + (88u << 20) + (384u << 10));      // 512 KB
    u16*   Wtb = (u16*)(ws + (88u << 20) + (896u << 10));      // 512 KB

    const size_t fixed = 90ull << 20;
    const size_t perG = (4ull << 20) + (1ull << 20) + (32ull << 10);
    int G = 0;
    for (int g = 16; g >= 1; g >>= 1)
        if (fixed + (size_t)g * perG <= ws_size) { G = g; break; }
    if (G == 0) G = 1;
    u8*    E0    = (u8*)(ws + fixed);
    float* Rpart = (float*)(ws + fixed + ((size_t)G << 22));
    float* Cpart = (float*)(ws + fixed + ((size_t)G << 22) + ((size_t)G << 20));

    k_cvt<<<32, 256, 0, stream>>>(WQ, WQb, DKK * DD);
    k_cvt<<<32, 256, 0, stream>>>(WK, WKb, DKK * DD);
    k_cvt<<<256, 256, 0, stream>>>(WV, WVb, DD * DD);
    k_cvt<<<256, 256, 0, stream>>>(Wt, Wtb, DD * DD);

    k_projqk<<<dim3(LQ / 128, BB, 2), 256, 0, stream>>>(query, key, WQb, WKb, wqb, wkb);

    for (int b0 = 0; b0 < BB; b0 += G) {
        k_score<<<dim3(LK / 128, LQ / 512, G), 256, 0, stream>>>(wqb, wkb, E0, Rpart, b0);
        k_rsum<<<G * 8, 256, 0, stream>>>(Rpart, Rq, b0);
        k_colsum<<<dim3(32, 4, G), 256, 0, stream>>>(E0, Rq, Cpart, b0);
        k_csum<<<G * 8, 256, 0, stream>>>(Cpart, ci, b0);
        k_projv<<<dim3(LK / 128, DD / 128, G), 256, 0, stream>>>(value, WVb, ci, wvS, b0);
        k_pvgemm<<<64 * G, 256, 0, stream>>>(query, E0, wvS, Rq, t, b0, G);
    }

    k_final<<<dim3(LQ * BB / 128, DD / 128), 256, 0, stream>>>(t, Wtb, out);
}

// Round 16
// 254.888 us; speedup vs baseline: 1.1913x; 1.0093x over previous
//
#include <hip/hip_runtime.h>

#define LQ 2048
#define LK 2048
#define BB 16
#define DD 512
#define DKK 64
#define EPSF 1e-9f

typedef unsigned short u16;
typedef unsigned char u8;
typedef long i64;
typedef __attribute__((ext_vector_type(8))) short bf16x8;
typedef __attribute__((ext_vector_type(4))) float f32x4;
#define MFMA16(a, b, c) __builtin_amdgcn_mfma_f32_16x16x32_bf16(a, b, c, 0, 0, 0)
#define MFMAF8(a, b, c) __builtin_amdgcn_mfma_f32_16x16x32_fp8_fp8(a, b, c, 0, 0, 0)

__device__ inline u16 f2bf(float f) {
    unsigned int u = __float_as_uint(f);
    u += 0x7fffu + ((u >> 16) & 1u);   // RNE
    return (u16)(u >> 16);
}
// hardware packed f32->bf16 (RNE), 2 elements/instruction
__device__ inline bf16x8 cvt8(float4 a, float4 b) {
    union { bf16x8 v; unsigned int u[4]; } r;
    asm("v_cvt_pk_bf16_f32 %0, %1, %2" : "=v"(r.u[0]) : "v"(a.x), "v"(a.y));
    asm("v_cvt_pk_bf16_f32 %0, %1, %2" : "=v"(r.u[1]) : "v"(a.z), "v"(a.w));
    asm("v_cvt_pk_bf16_f32 %0, %1, %2" : "=v"(r.u[2]) : "v"(b.x), "v"(b.y));
    asm("v_cvt_pk_bf16_f32 %0, %1, %2" : "=v"(r.u[3]) : "v"(b.z), "v"(b.w));
    return r.v;
}
__device__ inline int pk_fp8x4(float a, float b, float c, float d) {
    int r = __builtin_amdgcn_cvt_pk_fp8_f32(a, b, 0, false);
    r = __builtin_amdgcn_cvt_pk_fp8_f32(c, d, r, true);
    return r;
}
__device__ inline void gload16(const void* g, void* l) {
    __builtin_amdgcn_global_load_lds((const __attribute__((address_space(1))) unsigned int*)g,
                                     (__attribute__((address_space(3))) unsigned int*)l, 16, 0, 0);
}

__global__ __launch_bounds__(256) void k_cvt(const float* __restrict__ src, u16* __restrict__ dst, int n) {
    int i = (blockIdx.x * 256 + threadIdx.x) * 4;
    if (i < n) {
        float4 v = *reinterpret_cast<const float4*>(src + i);
        *reinterpret_cast<ushort4*>(dst + i) = make_ushort4(f2bf(v.x), f2bf(v.y), f2bf(v.z), f2bf(v.w));
    }
}

// fused q/k projection + l2norm.  Staged-async A + XOR swizzle; hw-cvt on read; B direct (L2).
__global__ __launch_bounds__(256) void k_projqk(const float* __restrict__ xq, const float* __restrict__ xk,
                                                const u16* __restrict__ Wq, const u16* __restrict__ Wk,
                                                u16* __restrict__ yq, u16* __restrict__ yk)
{
    const float* x = blockIdx.z ? xk : xq;
    const u16* Wb = blockIdx.z ? Wk : Wq;
    u16* y = blockIdx.z ? yk : yq;
    const int b = blockIdx.y, r0 = blockIdx.x * 128;
    const int tid = threadIdx.x, wv = tid >> 6, lane = tid & 63, l15 = lane & 15, g = lane >> 4;

    __shared__ __align__(16) float As[2][128 * 32];   // 2 x 16 KB

    const int srow = wv * 8 + (lane >> 3);
    const int scb = ((lane & 7) * 16) ^ ((srow & 7) << 4);

    f32x4 z = {0.f, 0.f, 0.f, 0.f};
    f32x4 acc[2][4];
#pragma unroll
    for (int m = 0; m < 2; m++)
#pragma unroll
        for (int nf = 0; nf < 4; nf++) acc[m][nf] = z;

    auto stage = [&](int buf, int kt) {
#pragma unroll
        for (int p = 0; p < 4; ++p) {
            const char* src = (const char*)(x + ((size_t)(r0 + p * 32 + srow) * BB + b) * DD) + kt * 4 + scb;
            gload16(src, (char*)As[buf] + p * 4096 + wv * 1024);
        }
    };
    stage(0, 0);
    int buf = 0;
    for (int tt = 0; tt < 16; ++tt) {
        __syncthreads();
        if (tt + 1 < 16) stage(buf ^ 1, (tt + 1) * 32);
        bf16x8 af[2];
#pragma unroll
        for (int m = 0; m < 2; m++) {
            int row = wv * 32 + m * 16 + l15;
            const char* rp = (const char*)As[buf] + row * 128;
            int xs = (row & 7) << 4;
            float4 fa = *reinterpret_cast<const float4*>(rp + ((g * 32) ^ xs));
            float4 fb = *reinterpret_cast<const float4*>(rp + ((g * 32 + 16) ^ xs));
            af[m] = cvt8(fa, fb);
        }
#pragma unroll
        for (int nf = 0; nf < 4; nf++) {
            bf16x8 bw = *reinterpret_cast<const bf16x8*>(Wb + (size_t)(nf * 16 + l15) * DD + tt * 32 + g * 8);
            acc[0][nf] = MFMA16(af[0], bw, acc[0][nf]);
            acc[1][nf] = MFMA16(af[1], bw, acc[1][nf]);
        }
        buf ^= 1;
    }
#pragma unroll
    for (int m = 0; m < 2; m++) {
        float rn[4];
#pragma unroll
        for (int j = 0; j < 4; j++) {
            float t2 = acc[m][0][j] * acc[m][0][j] + acc[m][1][j] * acc[m][1][j]
                     + acc[m][2][j] * acc[m][2][j] + acc[m][3][j] * acc[m][3][j];
            t2 += __shfl_xor(t2, 1, 64);
            t2 += __shfl_xor(t2, 2, 64);
            t2 += __shfl_xor(t2, 4, 64);
            t2 += __shfl_xor(t2, 8, 64);
            rn[j] = 1.f / fmaxf(sqrtf(t2), 1e-12f);
        }
#pragma unroll
        for (int nf = 0; nf < 4; nf++)
#pragma unroll
            for (int j = 0; j < 4; j++) {
                int q = r0 + wv * 32 + m * 16 + g * 4 + j;
                y[((size_t)b * LQ + q) * DKK + nf * 16 + l15] = f2bf(acc[m][nf][j] * rn[j]);
            }
    }
}

// Single QK^T pass, TILED E0 output. Each wave owns TWO k-tiles (2x MFMA ILP per Q-frag).
__global__ __launch_bounds__(256) void k_score(const u16* __restrict__ wqb, const u16* __restrict__ wkb,
                                               u8* __restrict__ E0t, float* __restrict__ Rpart, int b0)
{
    const int bx = blockIdx.x, qc = blockIdx.y, bl = blockIdx.z, b = b0 + bl;
    const int tid = threadIdx.x, w = tid >> 6, lane = tid & 63, l15 = lane & 15, g = lane >> 4;
    const int kt0 = bx * 8 + w * 2;
    f32x4 z = {0.f, 0.f, 0.f, 0.f};

    bf16x8 af[2][2];
#pragma unroll
    for (int j = 0; j < 2; j++) {
        const u16* ar = wkb + ((size_t)b * LK + (kt0 + j) * 16 + l15) * DKK;
        af[j][0] = *reinterpret_cast<const bf16x8*>(ar + g * 8);
        af[j][1] = *reinterpret_cast<const bf16x8*>(ar + 32 + g * 8);
    }
    u8* Eb = E0t + (size_t)bl * LQ * LK + l15 * 16 + g * 4;
    float* Rp0 = Rpart + ((size_t)bl * 128 + kt0) * LQ + qc * 512;
    float* Rp1 = Rp0 + LQ;
    const u16* qbase = wqb + ((size_t)b * LQ + qc * 512 + l15) * DKK + g * 8;

    bf16x8 c0 = *reinterpret_cast<const bf16x8*>(qbase);
    bf16x8 c1 = *reinterpret_cast<const bf16x8*>(qbase + 32);
    bf16x8 n0_ = c0, n1_ = c1;

#pragma unroll 4
    for (int qf = 0; qf < 32; qf++) {
        if (qf < 31) {
            const u16* br = qbase + (size_t)(qf + 1) * 16 * DKK;
            n0_ = *reinterpret_cast<const bf16x8*>(br);
            n1_ = *reinterpret_cast<const bf16x8*>(br + 32);
        }
        __builtin_amdgcn_sched_barrier(0);
        int qt = qc * 32 + qf;
#pragma unroll
        for (int j = 0; j < 2; j++) {
            f32x4 s = z;
            s = MFMA16(af[j][0], c0, s);
            s = MFMA16(af[j][1], c1, s);
            float pe0 = __expf(s[0]), pe1 = __expf(s[1]);
            float pe2 = __expf(s[2]), pe3 = __expf(s[3]);
            *reinterpret_cast<int*>(Eb + ((size_t)qt * 128 + kt0 + j) * 256) =
                pk_fp8x4(pe0, pe1, pe2, pe3);
            float v = pe0 + pe1 + pe2 + pe3;
            v += __shfl_xor(v, 16, 64);
            v += __shfl_xor(v, 32, 64);
            if (g == 0) (j ? Rp1 : Rp0)[qf * 16 + l15] = v;
        }
        c0 = n0_; c1 = n1_;
    }
}

// Rq[b][q] = 1 / sum_p Rpart[bl][p][q]
__global__ __launch_bounds__(256) void k_rsum(const float* __restrict__ Rpart, float* __restrict__ Rq, int b0) {
    int idx = blockIdx.x * 256 + threadIdx.x;
    int bl = idx >> 11, q = idx & 2047;
    const float* rp = Rpart + (size_t)bl * 128 * LQ + q;
    float s = 0.f;
    for (int p = 0; p < 128; p++) s += rp[(size_t)p * LQ];
    Rq[(size_t)(b0 + bl) * LQ + q] = 1.f / s;
}

// Cpart[bl][qc][k] = sum over 512 q (32 qt) of E0t[qt][kt]*Rq.  grid (32, 4, G)
__global__ __launch_bounds__(256) void k_colsum(const u8* __restrict__ E0t, const float* __restrict__ Rq,
                                                float* __restrict__ Cpart, int b0)
{
    const int qc = blockIdx.y, bl = blockIdx.z;
    const int tid = threadIdx.x, w = tid >> 6, lane = tid & 63, l15 = lane & 15, g = lane >> 4;
    const int kt = blockIdx.x * 4 + w;
    const u8* base = E0t + (size_t)bl * LQ * LK + (size_t)kt * 256 + l15 * 16 + g * 4;
    const float* rq = Rq + (size_t)(b0 + bl) * LQ;
    float acc[4] = {0.f, 0.f, 0.f, 0.f};
#pragma unroll 4
    for (int i = 0; i < 32; i++) {
        int qt = qc * 32 + i;
        unsigned int u = *reinterpret_cast<const unsigned int*>(base + (size_t)qt * 32768);
        float wgt = rq[qt * 16 + l15];
#pragma unroll
        for (int by = 0; by < 4; by++) {
            unsigned int f = 0x3C000000u + (((u >> (8 * by)) & 0x7Fu) << 20);
            acc[by] += __uint_as_float(f) * wgt;
        }
    }
#pragma unroll
    for (int by = 0; by < 4; by++) {
        acc[by] += __shfl_xor(acc[by], 1, 64);
        acc[by] += __shfl_xor(acc[by], 2, 64);
        acc[by] += __shfl_xor(acc[by], 4, 64);
        acc[by] += __shfl_xor(acc[by], 8, 64);
    }
    if (l15 == 0) {
        float4 v4 = make_float4(acc[0], acc[1], acc[2], acc[3]);
        *reinterpret_cast<float4*>(Cpart + ((size_t)bl * 4 + qc) * LK + kt * 16 + g * 4) = v4;
    }
}

// ci[b][k] = 1/(eps + sum_qc Cpart)
__global__ __launch_bounds__(256) void k_csum(const float* __restrict__ Cpart, float* __restrict__ ci, int b0) {
    int idx = blockIdx.x * 256 + threadIdx.x;
    int bl = idx >> 11, k = idx & 2047;
    const float* cp = Cpart + (size_t)bl * 4 * LK + k;
    float s = 0.f;
#pragma unroll
    for (int p = 0; p < 4; p++) s += cp[(size_t)p * LK];
    ci[(size_t)(b0 + bl) * LK + k] = 1.f / (EPSF + s);
}

// wvS[b][d][k] = fp8( (value[k,b,:] @ WVb[d,:]) * ci[b][k] )
// BK=64: 8 iterations, 32 MFMA per barrier. A f32 [128 rows][256B] dbuf (64 KB LDS),
// XOR swizzle per 128B half, applied on global source (dest linear, rule 21).
__global__ __launch_bounds__(256) void k_projv(const float* __restrict__ value, const u16* __restrict__ WVb,
                                               const float* __restrict__ ci, u8* __restrict__ wvS, int b0)
{
    const int b = b0 + blockIdx.z, k0 = blockIdx.x * 128, n0 = blockIdx.y * 128;
    const int tid = threadIdx.x, wv = tid >> 6, lane = tid & 63, l15 = lane & 15, g = lane >> 4;
    const int qg = wv >> 1, dg = wv & 1;

    __shared__ __align__(16) float As[2][128 * 64];   // 2 x 32 KB

    // staging geometry: one gload16 covers 4 rows x 256B; 8 per wave (rows wv*32 .. +31)
    const int rlane = lane >> 4;                                   // 0..3: row within 4-row group
    const int off_e = ((lane & 7) * 16) ^ (rlane << 4);            // swizzled in-half byte (p even)
    const int off_o = off_e ^ 64;                                  // p odd: (row&7) gains +4
    const int half = (lane & 8) ? 128 : 0;
    const char* vbase = (const char*)(value + ((size_t)(k0 + wv * 32 + rlane) * BB + b) * DD) + half;

    f32x4 z = {0.f, 0.f, 0.f, 0.f};
    f32x4 acc[4][4];
#pragma unroll
    for (int m = 0; m < 4; m++)
#pragma unroll
        for (int nf = 0; nf < 4; nf++) acc[m][nf] = z;

    auto stage = [&](int buf, int kt) {
#pragma unroll
        for (int p = 0; p < 8; ++p) {
            const char* src = vbase + (size_t)p * 4 * BB * DD * 4 + kt * 4 + ((p & 1) ? off_o : off_e);
            gload16(src, (char*)As[buf] + (wv * 32 + p * 4) * 256);
        }
    };
    stage(0, 0);
    int buf = 0;
    for (int tt = 0; tt < 8; ++tt) {
        __syncthreads();                        // stage into buf landed; readers of buf^1 done
        if (tt + 1 < 8) stage(buf ^ 1, (tt + 1) * 64);
        bf16x8 af[4][2];
#pragma unroll
        for (int m = 0; m < 4; m++) {
            int row = qg * 64 + m * 16 + l15;
            const char* rp = (const char*)As[buf] + row * 256;
            int xs = (row & 7) << 4;
#pragma unroll
            for (int kk = 0; kk < 2; kk++) {
                float4 fa = *reinterpret_cast<const float4*>(rp + kk * 128 + ((g * 32) ^ xs));
                float4 fb = *reinterpret_cast<const float4*>(rp + kk * 128 + ((g * 32 + 16) ^ xs));
                af[m][kk] = cvt8(fa, fb);
            }
        }
#pragma unroll
        for (int kk = 0; kk < 2; kk++)
#pragma unroll
            for (int nf = 0; nf < 4; nf++) {
                bf16x8 bw = *reinterpret_cast<const bf16x8*>(
                    WVb + (size_t)(n0 + dg * 64 + nf * 16 + l15) * DD + tt * 64 + kk * 32 + g * 8);
#pragma unroll
                for (int m = 0; m < 4; m++) acc[m][nf] = MFMA16(af[m][kk], bw, acc[m][nf]);
            }
        buf ^= 1;
    }
#pragma unroll
    for (int m = 0; m < 4; m++) {
        float cv[4];
        int kb = k0 + qg * 64 + m * 16 + g * 4;
#pragma unroll
        for (int j = 0; j < 4; j++) cv[j] = ci[(size_t)b * LK + kb + j];
#pragma unroll
        for (int nf = 0; nf < 4; nf++) {
            int d = n0 + dg * 64 + nf * 16 + l15;
            *reinterpret_cast<int*>(wvS + ((size_t)b * DD + d) * LK + kb) =
                pk_fp8x4(acc[m][nf][0] * cv[0], acc[m][nf][1] * cv[1],
                         acc[m][nf][2] * cv[2], acc[m][nf][3] * cv[3]);
        }
    }
}

// t[q,b,:] = query - Rq[q] * (E0t @ wvS^T).  fp8 GEMM, BK=128.
__global__ __launch_bounds__(256, 3) void k_pvgemm(const float* __restrict__ query,
                                                   const u8* __restrict__ E0t,
                                                   const u8* __restrict__ wvS,
                                                   const float* __restrict__ Rq,
                                                   u16* __restrict__ tout, int b0, int G)
{
    const int i = blockIdx.x;
    int bl, tile;
    if (G == 16) { bl = (i & 7) + 8 * (i >> 9); tile = (i >> 3) & 63; }
    else         { bl = i % G; tile = i / G; }
    const int b = b0 + bl;
    const int q0 = (tile >> 2) * 128, n0 = (tile & 3) * 128;
    const int tid = threadIdx.x, wv = tid >> 6, lane = tid & 63, l15 = lane & 15, g = lane >> 4;
    const int qg = wv >> 1, dg = wv & 1;

    __shared__ __align__(16) char As[16384], Bs[16384];

    const u8* Eb = E0t + (size_t)bl * LQ * LK;
    const u8* Vb = wvS + (size_t)b * DD * LK;

    const char* gAt = (const char*)Eb + (size_t)(q0 >> 4) * 128 * 256;
    const int srow = wv * 8 + (lane >> 3);
    const int scb = ((lane & 7) * 16) ^ ((srow & 7) << 4);
    const char* gB = (const char*)Vb + (size_t)(n0 + srow) * LK + scb;
    const size_t rstepB = (size_t)32 * LK;

    f32x4 z = {0.f, 0.f, 0.f, 0.f};
    f32x4 acc[4][4];
#pragma unroll
    for (int m = 0; m < 4; m++)
#pragma unroll
        for (int nf = 0; nf < 4; nf++) acc[m][nf] = z;

    auto stage = [&](int t) {
#pragma unroll
        for (int p = 0; p < 4; ++p) {
            int c = wv * 4 + p;
            gload16(gAt + ((size_t)(c >> 1) * 128 + t * 8) * 256 + (c & 1) * 1024 + lane * 16,
                    (char*)As + c * 1024);
            gload16(gB + p * rstepB + t * 128, (char*)Bs + p * 4096 + wv * 1024);
        }
    };
    stage(0);

    for (int t = 0; t < LK / 128; ++t) {
        __syncthreads();
        i64 af[4][4], bv[4][4];
#pragma unroll
        for (int m = 0; m < 4; m++) {
            const char* rp = (const char*)As + (qg * 4 + m) * 2048 + l15 * 16 + (g & 1) * 8;
#pragma unroll
            for (int kk = 0; kk < 4; kk++)
                af[m][kk] = *reinterpret_cast<const i64*>(rp + (kk * 2 + (g >> 1)) * 256);
        }
#pragma unroll
        for (int nf = 0; nf < 4; nf++) {
            int row = dg * 64 + nf * 16 + l15;
            const char* rp = (const char*)Bs + row * 128;
            int x = (row & 7) << 4;
#pragma unroll
            for (int kk = 0; kk < 4; kk++)
                bv[nf][kk] = *reinterpret_cast<const i64*>(rp + ((kk * 32 + g * 8) ^ x));
        }
        __syncthreads();
        if (t + 1 < LK / 128) stage(t + 1);
#pragma unroll
        for (int kk = 0; kk < 4; kk++)
#pragma unroll
            for (int nf = 0; nf < 4; nf++)
#pragma unroll
                for (int m = 0; m < 4; m++)
                    acc[m][nf] = MFMAF8(af[m][kk], bv[nf][kk], acc[m][nf]);
    }
#pragma unroll
    for (int m = 0; m < 4; m++) {
        float rqv[4];
#pragma unroll
        for (int j = 0; j < 4; j++)
            rqv[j] = Rq[(size_t)b * LQ + q0 + qg * 64 + m * 16 + g * 4 + j];
#pragma unroll
        for (int nf = 0; nf < 4; nf++)
#pragma unroll
            for (int j = 0; j < 4; j++) {
                int q = q0 + qg * 64 + m * 16 + g * 4 + j;
                int d = n0 + dg * 64 + nf * 16 + l15;
                size_t idx = ((size_t)q * BB + b) * DD + d;
                tout[idx] = f2bf(query[idx] - acc[m][nf][j] * rqv[j]);
            }
    }
}

// out = relu( t @ Wtb^T ): 128x128 tile, bf16 staged, K=512
__global__ __launch_bounds__(256, 3) void k_final(const u16* __restrict__ t, const u16* __restrict__ Wtb,
                                                  float* __restrict__ out)
{
    const int r0 = blockIdx.x * 128, n0 = blockIdx.y * 128;
    const int tid = threadIdx.x, wv = tid >> 6, lane = tid & 63, l15 = lane & 15, g = lane >> 4;
    const int qg = wv >> 1, dg = wv & 1;

    __shared__ __align__(16) u16 As[128 * 64], Bs[128 * 64];

    const int srow = wv * 8 + (lane >> 3);
    const int scb = ((lane & 7) * 16) ^ ((srow & 7) << 4);
    const char* gA = (const char*)(t + (size_t)(r0 + srow) * DD) + scb;
    const char* gB = (const char*)(Wtb + (size_t)(n0 + srow) * DD) + scb;
    const size_t rstep = (size_t)32 * DD * 2;

    f32x4 z = {0.f, 0.f, 0.f, 0.f};
    f32x4 acc[4][4];
#pragma unroll
    for (int m = 0; m < 4; m++)
#pragma unroll
        for (int nf = 0; nf < 4; nf++) acc[m][nf] = z;

#pragma unroll
    for (int p = 0; p < 4; ++p) {
        gload16(gA + p * rstep, (char*)As + p * 4096 + wv * 1024);
        gload16(gB + p * rstep, (char*)Bs + p * 4096 + wv * 1024);
    }

    for (int tt = 0; tt < DD / 64; ++tt) {
        __syncthreads();
        bf16x8 af[4][2], bv[4][2];
#pragma unroll
        for (int m = 0; m < 4; m++) {
            int row = qg * 64 + m * 16 + l15;
            const char* rp = (const char*)As + row * 128;
            int x = (row & 7) << 4;
#pragma unroll
            for (int kk = 0; kk < 2; kk++)
                af[m][kk] = *reinterpret_cast<const bf16x8*>(rp + ((kk * 64 + g * 16) ^ x));
        }
#pragma unroll
        for (int nf = 0; nf < 4; nf++) {
            int row = dg * 64 + nf * 16 + l15;
            const char* rp = (const char*)Bs + row * 128;
            int x = (row & 7) << 4;
#pragma unroll
            for (int kk = 0; kk < 2; kk++)
                bv[nf][kk] = *reinterpret_cast<const bf16x8*>(rp + ((kk * 64 + g * 16) ^ x));
        }
        __syncthreads();
        if (tt + 1 < DD / 64) {
            int ktb = (tt + 1) * 128;
#pragma unroll
            for (int p = 0; p < 4; ++p) {
                gload16(gA + p * rstep + ktb, (char*)As + p * 4096 + wv * 1024);
                gload16(gB + p * rstep + ktb, (char*)Bs + p * 4096 + wv * 1024);
            }
        }
#pragma unroll
        for (int nf = 0; nf < 4; nf++)
#pragma unroll
            for (int m = 0; m < 4; m++) {
                acc[m][nf] = MFMA16(af[m][0], bv[nf][0], acc[m][nf]);
                acc[m][nf] = MFMA16(af[m][1], bv[nf][1], acc[m][nf]);
            }
    }
#pragma unroll
    for (int m = 0; m < 4; m++)
#pragma unroll
        for (int nf = 0; nf < 4; nf++)
#pragma unroll
            for (int j = 0; j < 4; j++)
                out[(size_t)(r0 + qg * 64 + m * 16 + g * 4 + j) * DD + n0 + dg * 64 + nf * 16 + l15] =
                    fmaxf(acc[m][nf][j], 0.f);
}

extern "C" void kernel_launch(void* const* d_in, const int* in_sizes, int n_in,
                              void* d_out, int out_size, void* d_ws, size_t ws_size,
                              hipStream_t stream)
{
    const float* query = (const float*)d_in[0];
    const float* key   = (const float*)d_in[1];
    const float* value = (const float*)d_in[2];
    const float* WK    = (const float*)d_in[3];
    const float* WQ    = (const float*)d_in[4];
    const float* WV    = (const float*)d_in[5];
    const float* Wt    = (const float*)d_in[6];
    float* out = (float*)d_out;

    char* ws = (char*)d_ws;
    u16*   wqb = (u16*)(ws);                                   //  4 MB [B][LQ][64] bf16
    u16*   wkb = (u16*)(ws + (4u << 20));                      //  4 MB [B][LK][64] bf16
    u8*    wvS = (u8*)(ws + (8u << 20));                       // 16 MB [B][512][LK] fp8
    u16*   t   = (u16*)(ws + (24u << 20));                     // 32 MB [LQ][B][512] bf16
    float* Rq  = (float*)(ws + (88u << 20));                   // 128 KB [B][LQ] f32
    float* ci  = (float*)(ws + (88u << 20) + (128u << 10));    // 128 KB [B][LK] f32
    u16*   WQb = (u16*)(ws + (88u << 20) + (256u << 10));      // 64 KB
    u16*   WKb = (u16*)(ws + (88u << 20) + (320u << 10));      // 64 KB
    u16*   WVb = (u16*)(ws + (88u << 20) + (384u << 10));      // 512 KB
    u16*   Wtb = (u16*)(ws + (88u << 20) + (896u << 10));      // 512 KB

    const size_t fixed = 90ull << 20;
    const size_t perG = (4ull << 20) + (1ull << 20) + (32ull << 10);
    int G = 0;
    for (int g = 16; g >= 1; g >>= 1)
        if (fixed + (size_t)g * perG <= ws_size) { G = g; break; }
    if (G == 0) G = 1;
    u8*    E0    = (u8*)(ws + fixed);
    float* Rpart = (float*)(ws + fixed + ((size_t)G << 22));
    float* Cpart = (float*)(ws + fixed + ((size_t)G << 22) + ((size_t)G << 20));

    k_cvt<<<32, 256, 0, stream>>>(WQ, WQb, DKK * DD);
    k_cvt<<<32, 256, 0, stream>>>(WK, WKb, DKK * DD);
    k_cvt<<<256, 256, 0, stream>>>(WV, WVb, DD * DD);
    k_cvt<<<256, 256, 0, stream>>>(Wt, Wtb, DD * DD);

    k_projqk<<<dim3(LQ / 128, BB, 2), 256, 0, stream>>>(query, key, WQb, WKb, wqb, wkb);

    for (int b0 = 0; b0 < BB; b0 += G) {
        k_score<<<dim3(LK / 128, LQ / 512, G), 256, 0, stream>>>(wqb, wkb, E0, Rpart, b0);
        k_rsum<<<G * 8, 256, 0, stream>>>(Rpart, Rq, b0);
        k_colsum<<<dim3(32, 4, G), 256, 0, stream>>>(E0, Rq, Cpart, b0);
        k_csum<<<G * 8, 256, 0, stream>>>(Cpart, ci, b0);
        k_projv<<<dim3(LK / 128, DD / 128, G), 256, 0, stream>>>(value, WVb, ci, wvS, b0);
        k_pvgemm<<<64 * G, 256, 0, stream>>>(query, E0, wvS, Rq, t, b0, G);
    }

    k_final<<<dim3(LQ * BB / 128, DD / 128), 256, 0, stream>>>(t, Wtb, out);
}